// Round 3
// baseline (6734.052 us; speedup 1.0000x reference)
//
#include <hip/hip_runtime.h>
#include <hip/hip_bf16.h>

#define NN 100000
#define EE 1600000
#define RR 6
#define DIN 128
#define HH 64
#define SCAN_NBLK 25   // ceil(NN/4096)

// ---------------- setup kernels ----------------

__global__ __launch_bounds__(256) void zero_k(int* p, int n4) {
    int i = blockIdx.x * 256 + threadIdx.x;
    if (i < n4) ((int4*)p)[i] = make_int4(0, 0, 0, 0);
}

// W [R,3,Kin,64] -> out [R][Kin][192]: cols 0-63 = W0-W2, 64-127 = W1, 128-191 = W2
__global__ __launch_bounds__(256) void build_wcat_kernel(const float* __restrict__ W,
                                                         float* __restrict__ out, int Kin) {
    int idx = blockIdx.x * 256 + threadIdx.x;
    int total = RR * Kin * 192;
    if (idx >= total) return;
    int j = idx % 192;
    int rest = idx / 192;      // r*Kin + i
    int i = rest % Kin;
    int r = rest / Kin;
    int k = j >> 6, jj = j & 63;
    float v = W[(((size_t)r * 3 + k) * Kin + i) * 64 + jj];
    if (k == 0) v -= W[(((size_t)r * 3 + 2) * Kin + i) * 64 + jj];
    out[idx] = v;
}

__global__ __launch_bounds__(256) void count_k(const int* __restrict__ src,
                                               const int* __restrict__ dst,
                                               int* __restrict__ deg, int* __restrict__ cnt) {
    int e = blockIdx.x * 256 + threadIdx.x;   // EE divisible by 256
    atomicAdd(&deg[src[e]], 1);
    atomicAdd(&cnt[dst[e]], 1);
}

__global__ __launch_bounds__(256) void dis_k(const int* __restrict__ deg, float* __restrict__ dis) {
    int idx = blockIdx.x * 256 + threadIdx.x;
    if (idx >= NN) return;
    int d = deg[idx];
    dis[idx] = d > 0 ? rsqrtf((float)d) : 0.f;
}

// exclusive scan of cnt[0..NN) into rowp[0..NN); block totals into psum[blk]
__global__ __launch_bounds__(256) void scan1(const int* __restrict__ cnt,
                                             int* __restrict__ rowp, int* __restrict__ psum) {
    int blk = blockIdx.x;
    int tid = threadIdx.x;
    int base = blk * 4096 + tid * 16;
    int vals[16];
    int run = 0;
#pragma unroll
    for (int i = 0; i < 16; i++) {
        int idx = base + i;
        int v = (idx < NN) ? cnt[idx] : 0;
        vals[i] = run;
        run += v;
    }
    int lane = tid & 63, wv = tid >> 6;
    int x = run;
#pragma unroll
    for (int d = 1; d < 64; d <<= 1) {
        int y = __shfl_up(x, d, 64);
        if (lane >= d) x += y;
    }
    __shared__ int wsum[4];
    if (lane == 63) wsum[wv] = x;
    __syncthreads();
    int woff = 0;
    for (int wi = 0; wi < wv; ++wi) woff += wsum[wi];
    int texcl = woff + x - run;
#pragma unroll
    for (int i = 0; i < 16; i++) {
        int idx = base + i;
        if (idx < NN) rowp[idx] = texcl + vals[i];
    }
    if (tid == 255) psum[blk] = woff + x;   // block total
}

__global__ void scan2(int* psum) {
    if (threadIdx.x == 0) {
        int run = 0;
        for (int b = 0; b < SCAN_NBLK; b++) {
            int t = psum[b];
            psum[b] = run;
            run += t;
        }
    }
}

__global__ __launch_bounds__(256) void scan3(int* __restrict__ rowp, int* __restrict__ cursor,
                                             const int* __restrict__ psum) {
    int blk = blockIdx.x;
    int off = psum[blk];
    int tid = threadIdx.x;
    int base = blk * 4096 + tid * 16;
#pragma unroll
    for (int i = 0; i < 16; i++) {
        int idx = base + i;
        if (idx < NN) {
            int v = rowp[idx] + off;
            rowp[idx] = v;
            cursor[idx] = v;
        }
    }
    if (blk == 0 && tid == 0) rowp[NN] = EE;
}

__global__ __launch_bounds__(256) void fill_k(const int* __restrict__ src,
                                              const int* __restrict__ dst,
                                              int* __restrict__ cursor, int* __restrict__ csr) {
    int e = blockIdx.x * 256 + threadIdx.x;
    int s = src[e], d = dst[e];
    int pos = atomicAdd(&cursor[d], 1);
    if (pos >= 0 && pos < EE) csr[pos] = s;   // defensive: never write OOB
}

// ---------------- SpMM: out[n,:] = sum_{e: dst=n} -(dis[n]*dis[src]) * v[src,:]
__global__ __launch_bounds__(256) void spmm64(const float* __restrict__ v, int ldv,
                                              float* __restrict__ out,
                                              const int* __restrict__ csr,
                                              const int* __restrict__ rowp,
                                              const float* __restrict__ dis) {
    int w = threadIdx.x >> 6, lane = threadIdx.x & 63;
    int row = blockIdx.x * 4 + w;
    if (row >= NN) return;
    int s0 = rowp[row], s1 = rowp[row + 1];
    s0 = max(0, s0);
    s1 = min(EE, s1);          // defensive clamp
    float dd = -dis[row];
    float acc = 0.f;
    for (int e = s0; e < s1; ++e) {
        int s = csr[e];
        float wgt = dd * dis[s];
        acc = fmaf(wgt, v[(size_t)s * ldv + lane], acc);
    }
    out[(size_t)row * 64 + lane] = acc;
}

// w = y1 + 2z  (y1 is cols 0..63 of yb [N,128])
__global__ __launch_bounds__(256) void ew_w_kernel(float* __restrict__ yb, const float* __restrict__ zb) {
    int i = blockIdx.x * 256 + threadIdx.x;   // over NN*16 float4 groups
    if (i >= NN * 16) return;
    int n = i >> 4, c4 = (i & 15) * 4;
    float4 z = *(const float4*)(zb + (size_t)n * 64 + c4);
    float4* yp = (float4*)(yb + (size_t)n * 128 + c4);
    float4 y = *yp;
    y.x += 2.f * z.x; y.y += 2.f * z.y; y.z += 2.f * z.z; y.w += 2.f * z.w;
    *yp = y;
}

// ---------------- generic f32 GEMM: C = act(A@B + bias + add) ----------------

__device__ inline void store4(float* p, float4 v) { *(float4*)p = v; }
__device__ inline void store4(__hip_bfloat16* p, float4 v) {
    p[0] = __float2bfloat16(v.x);
    p[1] = __float2bfloat16(v.y);
    p[2] = __float2bfloat16(v.z);
    p[3] = __float2bfloat16(v.w);
}

// A [M,K] lda, B [K,Ncols] ldb (Ncols = gridDim.y*64), C ldc.
template <typename OT>
__global__ __launch_bounds__(256) void gemm64(const float* __restrict__ A, int lda,
                                              const float* __restrict__ B, int ldb,
                                              OT* __restrict__ C, int ldc,
                                              int M, int Kdim,
                                              const float* __restrict__ bias,
                                              const float* __restrict__ add, int ldadd,
                                              int do_relu) {
    __shared__ float As[32][68];
    __shared__ float Bs[32][68];
    const int tid = threadIdx.x;
    const int tx = tid & 15, ty = tid >> 4;
    const int row0 = blockIdx.x * 64;
    const int col0 = blockIdx.y * 64;
    const int ar = tid >> 2;
    const int ak = (tid & 3) * 8;
    const int br = tid >> 3;
    const int bc = (tid & 7) * 8;
    float acc[4][4];
#pragma unroll
    for (int i = 0; i < 4; i++)
#pragma unroll
        for (int j = 0; j < 4; j++) acc[i][j] = 0.f;

    for (int kt = 0; kt < Kdim; kt += 32) {
        float4 a0 = make_float4(0, 0, 0, 0), a1 = make_float4(0, 0, 0, 0);
        int grow = row0 + ar;
        if (grow < M) {
            const float* ap = A + (size_t)grow * lda + kt + ak;
            a0 = *(const float4*)ap;
            a1 = *(const float4*)(ap + 4);
        }
        const float* bp = B + (size_t)(kt + br) * ldb + col0 + bc;
        float4 b0 = *(const float4*)bp;
        float4 b1 = *(const float4*)(bp + 4);
        As[ak + 0][ar] = a0.x; As[ak + 1][ar] = a0.y; As[ak + 2][ar] = a0.z; As[ak + 3][ar] = a0.w;
        As[ak + 4][ar] = a1.x; As[ak + 5][ar] = a1.y; As[ak + 6][ar] = a1.z; As[ak + 7][ar] = a1.w;
        *(float4*)&Bs[br][bc] = b0;
        *(float4*)&Bs[br][bc + 4] = b1;
        __syncthreads();
#pragma unroll
        for (int kk = 0; kk < 32; kk++) {
            float4 av = *(const float4*)&As[kk][ty * 4];
            float4 bv = *(const float4*)&Bs[kk][tx * 4];
            float aa[4] = {av.x, av.y, av.z, av.w};
            float bb[4] = {bv.x, bv.y, bv.z, bv.w};
#pragma unroll
            for (int i = 0; i < 4; i++)
#pragma unroll
                for (int j = 0; j < 4; j++) acc[i][j] = fmaf(aa[i], bb[j], acc[i][j]);
        }
        __syncthreads();
    }
#pragma unroll
    for (int i = 0; i < 4; i++) {
        int row = row0 + ty * 4 + i;
        if (row >= M) continue;
        int col = col0 + tx * 4;
        float4 v = make_float4(acc[i][0], acc[i][1], acc[i][2], acc[i][3]);
        if (bias) {
            v.x += bias[col]; v.y += bias[col + 1]; v.z += bias[col + 2]; v.w += bias[col + 3];
        }
        if (add) {
            const float* ap = add + (size_t)row * ldadd + col;
            v.x += ap[0]; v.y += ap[1]; v.z += ap[2]; v.w += ap[3];
        }
        if (do_relu) {
            v.x = fmaxf(v.x, 0.f); v.y = fmaxf(v.y, 0.f); v.z = fmaxf(v.z, 0.f); v.w = fmaxf(v.w, 0.f);
        }
        store4(C + (size_t)row * ldc + col, v);
    }
}

// ---------------- epilogue ----------------

// one wave per (n,r): gate_logit = relu(stack[n,r,:]@gw1 + gb1) @ gw2 + gb2
__global__ __launch_bounds__(256) void gate_kernel(const __hip_bfloat16* __restrict__ stack,
                                                   const float* __restrict__ gw1,
                                                   const float* __restrict__ gb1,
                                                   const float* __restrict__ gw2,
                                                   const float* __restrict__ gb2,
                                                   float* __restrict__ glogit) {
    __shared__ float ws1[64 * 64];
    __shared__ float b1s[64];
    __shared__ float w2s[64];
    int tid = threadIdx.x;
    for (int i = tid; i < 1024; i += 256) ((float4*)ws1)[i] = ((const float4*)gw1)[i];
    if (tid < 64) { b1s[tid] = gb1[tid]; w2s[tid] = gw2[tid]; }
    __syncthreads();
    int w = tid >> 6, lane = tid & 63;
    int idx = blockIdx.x * 4 + w;
    if (idx >= NN * RR) return;
    float s = __bfloat162float(stack[(size_t)idx * 64 + lane]);
    float h = b1s[lane];
    for (int j = 0; j < 64; j++) h = fmaf(__shfl(s, j, 64), ws1[j * 64 + lane], h);
    h = fmaxf(h, 0.f);
    float p = h * w2s[lane];
#pragma unroll
    for (int d = 32; d >= 1; d >>= 1) p += __shfl_xor(p, d, 64);
    if (lane == 0) glogit[idx] = p + gb2[0];
}

// one wave per node: softmax over R, fuse, aux, proj, cls
__global__ __launch_bounds__(256) void final_kernel(const __hip_bfloat16* __restrict__ stack,
                                                    const float* __restrict__ glogit,
                                                    const float* __restrict__ pw,
                                                    const float* __restrict__ pb,
                                                    const float* __restrict__ cw1,
                                                    const float* __restrict__ cb1,
                                                    const float* __restrict__ cw2,
                                                    const float* __restrict__ cb2,
                                                    const float* __restrict__ auxw,
                                                    const float* __restrict__ auxb,
                                                    float* __restrict__ out) {
    __shared__ float pws[4096], cw1s[4096], auxws[RR * 64];
    __shared__ float pbs[64], cb1s[64], cw2s[64], auxbs[RR];
    int tid = threadIdx.x;
    for (int i = tid; i < 1024; i += 256) {
        ((float4*)pws)[i] = ((const float4*)pw)[i];
        ((float4*)cw1s)[i] = ((const float4*)cw1)[i];
    }
    for (int i = tid; i < RR * 16; i += 256) ((float4*)auxws)[i] = ((const float4*)auxw)[i];
    if (tid < 64) { pbs[tid] = pb[tid]; cb1s[tid] = cb1[tid]; cw2s[tid] = cw2[tid]; }
    if (tid < RR) auxbs[tid] = auxb[tid];
    __syncthreads();
    int w = tid >> 6, lane = tid & 63;
    int n = blockIdx.x * 4 + w;
    if (n >= NN) return;
    float gl[RR];
    float m = -1e30f;
#pragma unroll
    for (int r = 0; r < RR; r++) {
        gl[r] = glogit[(size_t)n * RR + r];
        m = fmaxf(m, gl[r]);
    }
    float ssum = 0.f;
#pragma unroll
    for (int r = 0; r < RR; r++) {
        gl[r] = __expf(gl[r] - m);
        ssum += gl[r];
    }
    float inv = 1.f / ssum;
    float hf = 0.f;
#pragma unroll
    for (int r = 0; r < RR; r++) {
        float s = __bfloat162float(stack[((size_t)n * RR + r) * 64 + lane]);
        hf = fmaf(gl[r] * inv, s, hf);
        float t = s * auxws[r * 64 + lane];
#pragma unroll
        for (int d = 32; d >= 1; d >>= 1) t += __shfl_xor(t, d, 64);
        if (lane == 0) out[NN + (size_t)n * RR + r] = t + auxbs[r];
    }
    float p = pbs[lane];
    for (int j = 0; j < 64; j++) p = fmaf(__shfl(hf, j, 64), pws[j * 64 + lane], p);
    p = fmaxf(p, 0.f);
    float c = cb1s[lane];
    for (int j = 0; j < 64; j++) c = fmaf(__shfl(p, j, 64), cw1s[j * 64 + lane], c);
    c = fmaxf(c, 0.f);
    float t = c * cw2s[lane];
#pragma unroll
    for (int d = 32; d >= 1; d >>= 1) t += __shfl_xor(t, d, 64);
    if (lane == 0) out[n] = t + cb2[0];
}

// ---------------- host ----------------

extern "C" void kernel_launch(void* const* d_in, const int* in_sizes, int n_in,
                              void* d_out, int out_size, void* d_ws, size_t ws_size,
                              hipStream_t stream) {
    const float* x = (const float*)d_in[0];
    const int* ei = (const int*)d_in[1];
    const float* c1w = (const float*)d_in[2];
    const float* c1b = (const float*)d_in[3];
    const float* c2w = (const float*)d_in[4];
    const float* c2b = (const float*)d_in[5];
    const float* gw1 = (const float*)d_in[6];
    const float* gb1 = (const float*)d_in[7];
    const float* gw2 = (const float*)d_in[8];
    const float* gb2 = (const float*)d_in[9];
    const float* pw = (const float*)d_in[10];
    const float* pb = (const float*)d_in[11];
    const float* cw1 = (const float*)d_in[12];
    const float* cb1 = (const float*)d_in[13];
    const float* cw2 = (const float*)d_in[14];
    const float* cb2 = (const float*)d_in[15];
    const float* auxw = (const float*)d_in[16];
    const float* auxb = (const float*)d_in[17];
    float* out = (float*)d_out;

    char* wsp = (char*)d_ws;
    size_t off = 0;
    auto carve = [&](size_t bytes) -> char* {
        char* p = wsp + off;
        off += (bytes + 255) & ~(size_t)255;
        return p;
    };
    __hip_bfloat16* stack = (__hip_bfloat16*)carve((size_t)NN * RR * 64 * 2);
    float* yb = (float*)carve((size_t)NN * 128 * 4);
    float* zb = (float*)carve((size_t)NN * 64 * 4);
    float* h1 = (float*)carve((size_t)NN * 64 * 4);
    float* dis = (float*)carve((size_t)NN * 4);
    int* deg = (int*)carve((size_t)2 * NN * 4);   // deg[0..NN) + cnt[NN..2NN) — ONE carve,
    int* cnt = deg + NN;                          // so the combined zero below is exact
    int* rowp = (int*)carve((size_t)(NN + 1) * 4);
    int* cursor = (int*)carve((size_t)NN * 4);
    int* csr = (int*)carve((size_t)EE * 4);
    int* psum = (int*)carve((size_t)32 * 4);
    float* wcat1 = (float*)carve((size_t)RR * 128 * 192 * 4);
    float* wcat2 = (float*)carve((size_t)RR * 64 * 192 * 4);
    float* glogit = (float*)carve((size_t)NN * RR * 4);
    (void)in_sizes; (void)n_in; (void)out_size;

    // Workspace guard: if insufficient, launch nothing (clean absmax-fail => ws too small).
    if (off > ws_size) return;

    build_wcat_kernel<<<(RR * 128 * 192) / 256, 256, 0, stream>>>(c1w, wcat1, 128);
    build_wcat_kernel<<<(RR * 64 * 192) / 256, 256, 0, stream>>>(c2w, wcat2, 64);

    const int MB = (NN + 63) / 64;   // 1563
    for (int r = 0; r < RR; ++r) {
        const int* src = ei + (size_t)r * 2 * EE;
        const int* dst = src + EE;
        const float* W1r = wcat1 + (size_t)r * 128 * 192;
        const float* W2r = wcat2 + (size_t)r * 64 * 192;

        // --- per-relation CSR (dst-major) + dis ---
        zero_k<<<(2 * NN / 4 + 255) / 256, 256, 0, stream>>>(deg, 2 * NN / 4);
        count_k<<<EE / 256, 256, 0, stream>>>(src, dst, deg, cnt);
        dis_k<<<(NN + 255) / 256, 256, 0, stream>>>(deg, dis);
        scan1<<<SCAN_NBLK, 256, 0, stream>>>(cnt, rowp, psum);
        scan2<<<1, 64, 0, stream>>>(psum);
        scan3<<<SCAN_NBLK, 256, 0, stream>>>(rowp, cursor, psum);
        fill_k<<<EE / 256, 256, 0, stream>>>(src, dst, cursor, csr);

        // layer 1: y12 = x@[W1|W2]; z = L(y2); w = y1+2z (in yb); s = L(w) (in zb);
        //          h1 = relu(x@(W0-W2) + s + b)
        gemm64<float><<<dim3(MB, 2), 256, 0, stream>>>(x, 128, W1r + 64, 192, yb, 128, NN, 128,
                                                       nullptr, nullptr, 0, 0);
        spmm64<<<NN / 4, 256, 0, stream>>>(yb + 64, 128, zb, csr, rowp, dis);
        ew_w_kernel<<<NN * 16 / 256, 256, 0, stream>>>(yb, zb);
        spmm64<<<NN / 4, 256, 0, stream>>>(yb, 128, zb, csr, rowp, dis);
        gemm64<float><<<dim3(MB, 1), 256, 0, stream>>>(x, 128, W1r, 192, h1, 64, NN, 128,
                                                       c1b + r * 64, zb, 64, 1);
        // layer 2
        gemm64<float><<<dim3(MB, 2), 256, 0, stream>>>(h1, 64, W2r + 64, 192, yb, 128, NN, 64,
                                                       nullptr, nullptr, 0, 0);
        spmm64<<<NN / 4, 256, 0, stream>>>(yb + 64, 128, zb, csr, rowp, dis);
        ew_w_kernel<<<NN * 16 / 256, 256, 0, stream>>>(yb, zb);
        spmm64<<<NN / 4, 256, 0, stream>>>(yb, 128, zb, csr, rowp, dis);
        gemm64<__hip_bfloat16><<<dim3(MB, 1), 256, 0, stream>>>(h1, 64, W2r, 192,
                                                                stack + r * 64, RR * 64, NN, 64,
                                                                c2b + r * 64, zb, 64, 1);
    }
    gate_kernel<<<(NN * RR) / 4, 256, 0, stream>>>(stack, gw1, gb1, gw2, gb2, glogit);
    final_kernel<<<NN / 4, 256, 0, stream>>>(stack, glogit, pw, pb, cw1, cb1, cw2, cb2,
                                             auxw, auxb, out);
}

// Round 4
// 4283.515 us; speedup vs baseline: 1.5721x; 1.5721x over previous
//
#include <hip/hip_runtime.h>
#include <hip/hip_bf16.h>

#define NN 100000
#define EE 1600000
#define RR 6
#define SCAN_NBLK 25   // ceil(NN/4096)

typedef __attribute__((ext_vector_type(8))) short bf16x8;
typedef __attribute__((ext_vector_type(4))) float f32x4;

__device__ inline short f2b(float x) {
    __hip_bfloat16 h = __float2bfloat16(x);
    return *reinterpret_cast<short*>(&h);
}
__device__ inline float b2f(short s) {
    __hip_bfloat16 h = *reinterpret_cast<__hip_bfloat16*>(&s);
    return __bfloat162float(h);
}

// ---------------- CSR build (unchanged from round 3) ----------------

__global__ __launch_bounds__(256) void zero_k(int* p, int n4) {
    int i = blockIdx.x * 256 + threadIdx.x;
    if (i < n4) ((int4*)p)[i] = make_int4(0, 0, 0, 0);
}

__global__ __launch_bounds__(256) void count_k(const int* __restrict__ src,
                                               const int* __restrict__ dst,
                                               int* __restrict__ deg, int* __restrict__ cnt) {
    int e = blockIdx.x * 256 + threadIdx.x;
    atomicAdd(&deg[src[e]], 1);
    atomicAdd(&cnt[dst[e]], 1);
}

__global__ __launch_bounds__(256) void dis_k(const int* __restrict__ deg, float* __restrict__ dis) {
    int idx = blockIdx.x * 256 + threadIdx.x;
    if (idx >= NN) return;
    int d = deg[idx];
    dis[idx] = d > 0 ? rsqrtf((float)d) : 0.f;
}

__global__ __launch_bounds__(256) void scan1(const int* __restrict__ cnt,
                                             int* __restrict__ rowp, int* __restrict__ psum) {
    int blk = blockIdx.x;
    int tid = threadIdx.x;
    int base = blk * 4096 + tid * 16;
    int vals[16];
    int run = 0;
#pragma unroll
    for (int i = 0; i < 16; i++) {
        int idx = base + i;
        int v = (idx < NN) ? cnt[idx] : 0;
        vals[i] = run;
        run += v;
    }
    int lane = tid & 63, wv = tid >> 6;
    int x = run;
#pragma unroll
    for (int d = 1; d < 64; d <<= 1) {
        int y = __shfl_up(x, d, 64);
        if (lane >= d) x += y;
    }
    __shared__ int wsum[4];
    if (lane == 63) wsum[wv] = x;
    __syncthreads();
    int woff = 0;
    for (int wi = 0; wi < wv; ++wi) woff += wsum[wi];
    int texcl = woff + x - run;
#pragma unroll
    for (int i = 0; i < 16; i++) {
        int idx = base + i;
        if (idx < NN) rowp[idx] = texcl + vals[i];
    }
    if (tid == 255) psum[blk] = woff + x;
}

__global__ void scan2(int* psum) {
    if (threadIdx.x == 0) {
        int run = 0;
        for (int b = 0; b < SCAN_NBLK; b++) {
            int t = psum[b];
            psum[b] = run;
            run += t;
        }
    }
}

__global__ __launch_bounds__(256) void scan3(int* __restrict__ rowp, int* __restrict__ cursor,
                                             const int* __restrict__ psum) {
    int blk = blockIdx.x;
    int off = psum[blk];
    int tid = threadIdx.x;
    int base = blk * 4096 + tid * 16;
#pragma unroll
    for (int i = 0; i < 16; i++) {
        int idx = base + i;
        if (idx < NN) {
            int v = rowp[idx] + off;
            rowp[idx] = v;
            cursor[idx] = v;
        }
    }
    if (blk == 0 && tid == 0) rowp[NN] = EE;
}

__global__ __launch_bounds__(256) void fill_k(const int* __restrict__ src,
                                              const int* __restrict__ dst,
                                              int* __restrict__ cursor, int* __restrict__ csr) {
    int e = blockIdx.x * 256 + threadIdx.x;
    int s = src[e], d = dst[e];
    int pos = atomicAdd(&cursor[d], 1);
    if (pos >= 0 && pos < EE) csr[pos] = s;
}

// ---------------- weight packing into MFMA B-fragment order, hi/lo bf16 ----------------
// B frag for mfma_f32_16x16x32_bf16: lane l holds B[k = s*32 + (l>>4)*8 + j][n = t*16 + (l&15)]
// flat: bp[(((t)*KS + s)*64 + l)*8 + j], per-relation stride 12*KS*64*8.
// W [R,3,Kin,64]; wcat cols: 0-63 = W0-W2 (ntiles 0-3), 64-127 = W1 (4-7), 128-191 = W2 (8-11).
__global__ __launch_bounds__(256) void wpack_cheb(const float* __restrict__ W, int Kin, int KS,
                                                  short* __restrict__ bh, short* __restrict__ bl) {
    int idx = blockIdx.x * 256 + threadIdx.x;   // over R*12*KS*64
    int l = idx & 63;
    int q = idx >> 6;
    int s = q % KS; q /= KS;
    int t = q % 12; q /= 12;
    int r = q;
    if (r >= RR) return;
#pragma unroll
    for (int j = 0; j < 8; ++j) {
        int k = s * 32 + ((l >> 4) * 8) + j;
        int n = t * 16 + (l & 15);
        int g = n >> 6, jj = n & 63;
        float v = W[(((size_t)r * 3 + (g == 0 ? 0 : g)) * Kin + k) * 64 + jj];
        if (g == 0) v -= W[(((size_t)r * 3 + 2) * Kin + k) * 64 + jj];
        short hi = f2b(v);
        short lo = f2b(v - b2f(hi));
        bh[(size_t)idx * 8 + j] = hi;
        bl[(size_t)idx * 8 + j] = lo;
    }
}

// gw1 [64,64] -> packed (4 ntiles x 2 ksteps)
__global__ __launch_bounds__(256) void wpack_g1(const float* __restrict__ gw1,
                                                short* __restrict__ bh, short* __restrict__ bl) {
    int idx = blockIdx.x * 256 + threadIdx.x;   // over 4*2*64 = 512
    if (idx >= 512) return;
    int l = idx & 63;
    int s = (idx >> 6) & 1;
    int t = idx >> 7;
#pragma unroll
    for (int j = 0; j < 8; ++j) {
        int k = s * 32 + ((l >> 4) * 8) + j;
        int n = t * 16 + (l & 15);
        float v = gw1[k * 64 + n];
        short hi = f2b(v);
        short lo = f2b(v - b2f(hi));
        bh[(size_t)idx * 8 + j] = hi;
        bl[(size_t)idx * 8 + j] = lo;
    }
}

// ---------------- MFMA GEMM ----------------
// C[M x ntn*16] = A[M x KDIM] @ Bpack(ntiles nt0..nt0+ntn-1), + bias + add, relu, rowscale.
// A: f32 (AF32=1, on-the-fly bf16 cvt) or bf16. Out: f32 (outf) or bf16 (outb).
template <int KDIM, int AF32>
__global__ __launch_bounds__(256) void gemm_mfma(const void* __restrict__ Av, int lda,
                                                 const short* __restrict__ bph,
                                                 const short* __restrict__ bplo,
                                                 int nt0, int ntn,
                                                 float* __restrict__ outf,
                                                 short* __restrict__ outb, int ldc,
                                                 const float* __restrict__ bias,
                                                 const float* __restrict__ add, int ldadd,
                                                 const float* __restrict__ rowscale,
                                                 int do_relu) {
    constexpr int KS = KDIM / 32;
    int w = threadIdx.x >> 6, l = threadIdx.x & 63;
    int rows0 = blockIdx.x * 64 + w * 16;
    int arow = rows0 + (l & 15);
    int kbase = (l >> 4) * 8;
    bf16x8 af[KS];
    if (AF32) {
        const float* A = (const float*)Av;
#pragma unroll
        for (int s = 0; s < KS; ++s) {
            bf16x8 t = {0, 0, 0, 0, 0, 0, 0, 0};
            if (arow < NN) {
                const float* p = A + (size_t)arow * lda + s * 32 + kbase;
                float4 u0 = *(const float4*)p;
                float4 u1 = *(const float4*)(p + 4);
                t[0] = f2b(u0.x); t[1] = f2b(u0.y); t[2] = f2b(u0.z); t[3] = f2b(u0.w);
                t[4] = f2b(u1.x); t[5] = f2b(u1.y); t[6] = f2b(u1.z); t[7] = f2b(u1.w);
            }
            af[s] = t;
        }
    } else {
        const short* A = (const short*)Av;
#pragma unroll
        for (int s = 0; s < KS; ++s) {
            bf16x8 t = {0, 0, 0, 0, 0, 0, 0, 0};
            if (arow < NN) t = *(const bf16x8*)(A + (size_t)arow * lda + s * 32 + kbase);
            af[s] = t;
        }
    }
    for (int t = 0; t < ntn; ++t) {
        f32x4 acc = {0.f, 0.f, 0.f, 0.f};
        const short* bp0 = bph + (((size_t)(nt0 + t) * KS) * 64 + l) * 8;
        const short* bl0 = bplo + (((size_t)(nt0 + t) * KS) * 64 + l) * 8;
#pragma unroll
        for (int s = 0; s < KS; ++s) {
            bf16x8 bh = *(const bf16x8*)(bp0 + (size_t)s * 64 * 8);
            bf16x8 bl = *(const bf16x8*)(bl0 + (size_t)s * 64 * 8);
            acc = __builtin_amdgcn_mfma_f32_16x16x32_bf16(af[s], bh, acc, 0, 0, 0);
            acc = __builtin_amdgcn_mfma_f32_16x16x32_bf16(af[s], bl, acc, 0, 0, 0);
        }
        int col = t * 16 + (l & 15);
#pragma unroll
        for (int r_ = 0; r_ < 4; ++r_) {
            int row = rows0 + (l >> 4) * 4 + r_;
            if (row >= NN) continue;
            float v = acc[r_];
            if (bias) v += bias[col];
            if (add) v += add[(size_t)row * ldadd + col];
            if (do_relu) v = fmaxf(v, 0.f);
            if (rowscale) v *= rowscale[row];
            if (outf) outf[(size_t)row * ldc + col] = v;
            else outb[(size_t)row * ldc + col] = f2b(v);
        }
    }
}

// ---------------- SpMM: out[n,:] = scale(n) * sum_{e: dst=n} v[src,:]  (weights pre-folded)
__global__ __launch_bounds__(256) void spmm_f(const float* __restrict__ v, int ldv,
                                              float* __restrict__ out,
                                              const int* __restrict__ csr,
                                              const int* __restrict__ rowp,
                                              const float* __restrict__ dis, int sq) {
    int w = threadIdx.x >> 6, lane = threadIdx.x & 63;
    int row = blockIdx.x * 4 + w;
    if (row >= NN) return;
    int s0 = max(0, rowp[row]);
    int s1 = min(EE, rowp[row + 1]);
    float acc = 0.f;
    int e = s0;
    for (; e + 4 <= s1; e += 4) {
        int i0 = csr[e], i1 = csr[e + 1], i2 = csr[e + 2], i3 = csr[e + 3];
        float a = v[(size_t)i0 * ldv + lane];
        float b = v[(size_t)i1 * ldv + lane];
        float c = v[(size_t)i2 * ldv + lane];
        float d = v[(size_t)i3 * ldv + lane];
        acc += (a + b) + (c + d);
    }
    for (; e < s1; ++e) acc += v[(size_t)csr[e] * ldv + lane];
    float d = dis[row];
    float sc = sq ? -d * d : -d;
    out[(size_t)row * 64 + lane] = sc * acc;
}

// w' = y1' + 2z'  (y1' is cols 0..63 of yb [N,128], all pre-scaled by dis)
__global__ __launch_bounds__(256) void ew_w_kernel(float* __restrict__ yb, const float* __restrict__ zb) {
    int i = blockIdx.x * 256 + threadIdx.x;
    if (i >= NN * 16) return;
    int n = i >> 4, c4 = (i & 15) * 4;
    float4 z = *(const float4*)(zb + (size_t)n * 64 + c4);
    float4* yp = (float4*)(yb + (size_t)n * 128 + c4);
    float4 y = *yp;
    y.x += 2.f * z.x; y.y += 2.f * z.y; y.z += 2.f * z.z; y.w += 2.f * z.w;
    *yp = y;
}

// ---------------- gate via MFMA: glogit = relu(stack@gw1+gb1)@gw2 + gb2 ----------------
__global__ __launch_bounds__(256) void gate_mfma(const short* __restrict__ stack,
                                                 const short* __restrict__ g1h,
                                                 const short* __restrict__ g1l,
                                                 const float* __restrict__ gb1,
                                                 const float* __restrict__ gw2,
                                                 const float* __restrict__ gb2,
                                                 float* __restrict__ glogit) {
    int w = threadIdx.x >> 6, l = threadIdx.x & 63;
    int rows0 = blockIdx.x * 64 + w * 16;      // 9375*64 == 600000 exactly
    int arow = rows0 + (l & 15);
    int kbase = (l >> 4) * 8;
    bf16x8 af[2];
#pragma unroll
    for (int s = 0; s < 2; ++s)
        af[s] = *(const bf16x8*)(stack + (size_t)arow * 64 + s * 32 + kbase);
    float p[4] = {0.f, 0.f, 0.f, 0.f};
#pragma unroll
    for (int t = 0; t < 4; ++t) {
        f32x4 acc = {0.f, 0.f, 0.f, 0.f};
#pragma unroll
        for (int s = 0; s < 2; ++s) {
            bf16x8 bh = *(const bf16x8*)(g1h + (((size_t)t * 2 + s) * 64 + l) * 8);
            bf16x8 bl = *(const bf16x8*)(g1l + (((size_t)t * 2 + s) * 64 + l) * 8);
            acc = __builtin_amdgcn_mfma_f32_16x16x32_bf16(af[s], bh, acc, 0, 0, 0);
            acc = __builtin_amdgcn_mfma_f32_16x16x32_bf16(af[s], bl, acc, 0, 0, 0);
        }
        int col = t * 16 + (l & 15);
        float b = gb1[col], w2 = gw2[col];
#pragma unroll
        for (int r_ = 0; r_ < 4; ++r_) {
            float h = fmaxf(acc[r_] + b, 0.f);
            p[r_] = fmaf(h, w2, p[r_]);
        }
    }
#pragma unroll
    for (int d = 1; d < 16; d <<= 1) {
#pragma unroll
        for (int r_ = 0; r_ < 4; ++r_) p[r_] += __shfl_xor(p[r_], d, 64);
    }
    if ((l & 15) == 0) {
        float g2 = gb2[0];
#pragma unroll
        for (int r_ = 0; r_ < 4; ++r_) glogit[rows0 + (l >> 4) * 4 + r_] = p[r_] + g2;
    }
}

// ---------------- final: softmax over R, fuse, aux, proj, cls (unchanged) ----------------
__global__ __launch_bounds__(256) void final_kernel(const __hip_bfloat16* __restrict__ stack,
                                                    const float* __restrict__ glogit,
                                                    const float* __restrict__ pw,
                                                    const float* __restrict__ pb,
                                                    const float* __restrict__ cw1,
                                                    const float* __restrict__ cb1,
                                                    const float* __restrict__ cw2,
                                                    const float* __restrict__ cb2,
                                                    const float* __restrict__ auxw,
                                                    const float* __restrict__ auxb,
                                                    float* __restrict__ out) {
    __shared__ float pws[4096], cw1s[4096], auxws[RR * 64];
    __shared__ float pbs[64], cb1s[64], cw2s[64], auxbs[RR];
    int tid = threadIdx.x;
    for (int i = tid; i < 1024; i += 256) {
        ((float4*)pws)[i] = ((const float4*)pw)[i];
        ((float4*)cw1s)[i] = ((const float4*)cw1)[i];
    }
    for (int i = tid; i < RR * 16; i += 256) ((float4*)auxws)[i] = ((const float4*)auxw)[i];
    if (tid < 64) { pbs[tid] = pb[tid]; cb1s[tid] = cb1[tid]; cw2s[tid] = cw2[tid]; }
    if (tid < RR) auxbs[tid] = auxb[tid];
    __syncthreads();
    int w = tid >> 6, lane = tid & 63;
    int n = blockIdx.x * 4 + w;
    if (n >= NN) return;
    float gl[RR];
    float m = -1e30f;
#pragma unroll
    for (int r = 0; r < RR; r++) {
        gl[r] = glogit[(size_t)n * RR + r];
        m = fmaxf(m, gl[r]);
    }
    float ssum = 0.f;
#pragma unroll
    for (int r = 0; r < RR; r++) {
        gl[r] = __expf(gl[r] - m);
        ssum += gl[r];
    }
    float inv = 1.f / ssum;
    float hf = 0.f;
#pragma unroll
    for (int r = 0; r < RR; r++) {
        float s = __bfloat162float(stack[((size_t)n * RR + r) * 64 + lane]);
        hf = fmaf(gl[r] * inv, s, hf);
        float t = s * auxws[r * 64 + lane];
#pragma unroll
        for (int d = 32; d >= 1; d >>= 1) t += __shfl_xor(t, d, 64);
        if (lane == 0) out[NN + (size_t)n * RR + r] = t + auxbs[r];
    }
    float p = pbs[lane];
    for (int j = 0; j < 64; j++) p = fmaf(__shfl(hf, j, 64), pws[j * 64 + lane], p);
    p = fmaxf(p, 0.f);
    float c = cb1s[lane];
    for (int j = 0; j < 64; j++) c = fmaf(__shfl(p, j, 64), cw1s[j * 64 + lane], c);
    c = fmaxf(c, 0.f);
    float t = c * cw2s[lane];
#pragma unroll
    for (int d = 32; d >= 1; d >>= 1) t += __shfl_xor(t, d, 64);
    if (lane == 0) out[n] = t + cb2[0];
}

// ---------------- host ----------------

extern "C" void kernel_launch(void* const* d_in, const int* in_sizes, int n_in,
                              void* d_out, int out_size, void* d_ws, size_t ws_size,
                              hipStream_t stream) {
    const float* x = (const float*)d_in[0];
    const int* ei = (const int*)d_in[1];
    const float* c1w = (const float*)d_in[2];
    const float* c1b = (const float*)d_in[3];
    const float* c2w = (const float*)d_in[4];
    const float* c2b = (const float*)d_in[5];
    const float* gw1 = (const float*)d_in[6];
    const float* gb1 = (const float*)d_in[7];
    const float* gw2 = (const float*)d_in[8];
    const float* gb2 = (const float*)d_in[9];
    const float* pw = (const float*)d_in[10];
    const float* pb = (const float*)d_in[11];
    const float* cw1 = (const float*)d_in[12];
    const float* cb1 = (const float*)d_in[13];
    const float* cw2 = (const float*)d_in[14];
    const float* cb2 = (const float*)d_in[15];
    const float* auxw = (const float*)d_in[16];
    const float* auxb = (const float*)d_in[17];
    float* out = (float*)d_out;

    char* wsp = (char*)d_ws;
    size_t off = 0;
    auto carve = [&](size_t bytes) -> char* {
        char* p = wsp + off;
        off += (bytes + 255) & ~(size_t)255;
        return p;
    };
    short* stack = (short*)carve((size_t)NN * RR * 64 * 2);        // bf16 [N][R][64]
    float* yb = (float*)carve((size_t)NN * 128 * 4);               // y12' (dis-scaled)
    float* zb = (float*)carve((size_t)NN * 64 * 4);
    short* h1 = (short*)carve((size_t)NN * 64 * 2);                // bf16
    float* dis = (float*)carve((size_t)NN * 4);
    int* deg = (int*)carve((size_t)2 * NN * 4);                    // deg + cnt, one carve
    int* cnt = deg + NN;
    int* rowp = (int*)carve((size_t)(NN + 1) * 4);
    int* cursor = (int*)carve((size_t)NN * 4);
    int* csr = (int*)carve((size_t)EE * 4);
    int* psum = (int*)carve((size_t)32 * 4);
    short* bp1h = (short*)carve((size_t)RR * 12 * 4 * 64 * 8 * 2);
    short* bp1l = (short*)carve((size_t)RR * 12 * 4 * 64 * 8 * 2);
    short* bp2h = (short*)carve((size_t)RR * 12 * 2 * 64 * 8 * 2);
    short* bp2l = (short*)carve((size_t)RR * 12 * 2 * 64 * 8 * 2);
    short* g1h = (short*)carve((size_t)512 * 8 * 2);
    short* g1l = (short*)carve((size_t)512 * 8 * 2);
    float* glogit = (float*)carve((size_t)NN * RR * 4);
    (void)in_sizes; (void)n_in; (void)out_size;

    if (off > ws_size) return;   // guard: clean absmax-fail => ws too small

    wpack_cheb<<<72, 256, 0, stream>>>(c1w, 128, 4, bp1h, bp1l);
    wpack_cheb<<<36, 256, 0, stream>>>(c2w, 64, 2, bp2h, bp2l);
    wpack_g1<<<2, 256, 0, stream>>>(gw1, g1h, g1l);

    const int GB = 1563;   // ceil(NN/64)
    for (int r = 0; r < RR; ++r) {
        const int* src = ei + (size_t)r * 2 * EE;
        const int* dst = src + EE;
        const short* b1h = bp1h + (size_t)r * 12 * 4 * 64 * 8;
        const short* b1l = bp1l + (size_t)r * 12 * 4 * 64 * 8;
        const short* b2h = bp2h + (size_t)r * 12 * 2 * 64 * 8;
        const short* b2l = bp2l + (size_t)r * 12 * 2 * 64 * 8;

        // per-relation CSR (dst-major) + dis
        zero_k<<<(2 * NN / 4 + 255) / 256, 256, 0, stream>>>(deg, 2 * NN / 4);
        count_k<<<EE / 256, 256, 0, stream>>>(src, dst, deg, cnt);
        dis_k<<<(NN + 255) / 256, 256, 0, stream>>>(deg, dis);
        scan1<<<SCAN_NBLK, 256, 0, stream>>>(cnt, rowp, psum);
        scan2<<<1, 64, 0, stream>>>(psum);
        scan3<<<SCAN_NBLK, 256, 0, stream>>>(rowp, cursor, psum);
        fill_k<<<EE / 256, 256, 0, stream>>>(src, dst, cursor, csr);

        // layer 1: y12' = dis*(x@[W1|W2]); z' = -dis^2*sum y2'; w' = y1'+2z';
        //          s = -dis*sum w'; h1 = relu(x@(W0-W2) + s + b1)  [bf16]
        gemm_mfma<128, 1><<<GB, 256, 0, stream>>>(x, 128, b1h, b1l, 4, 8,
                                                  yb, nullptr, 128,
                                                  nullptr, nullptr, 0, dis, 0);
        spmm_f<<<NN / 4, 256, 0, stream>>>(yb + 64, 128, zb, csr, rowp, dis, 1);
        ew_w_kernel<<<NN * 16 / 256, 256, 0, stream>>>(yb, zb);
        spmm_f<<<NN / 4, 256, 0, stream>>>(yb, 128, zb, csr, rowp, dis, 0);
        gemm_mfma<128, 1><<<GB, 256, 0, stream>>>(x, 128, b1h, b1l, 0, 4,
                                                  nullptr, h1, 64,
                                                  c1b + r * 64, zb, 64, nullptr, 1);
        // layer 2 (A = h1 bf16, K=64)
        gemm_mfma<64, 0><<<GB, 256, 0, stream>>>(h1, 64, b2h, b2l, 4, 8,
                                                 yb, nullptr, 128,
                                                 nullptr, nullptr, 0, dis, 0);
        spmm_f<<<NN / 4, 256, 0, stream>>>(yb + 64, 128, zb, csr, rowp, dis, 1);
        ew_w_kernel<<<NN * 16 / 256, 256, 0, stream>>>(yb, zb);
        spmm_f<<<NN / 4, 256, 0, stream>>>(yb, 128, zb, csr, rowp, dis, 0);
        gemm_mfma<64, 0><<<GB, 256, 0, stream>>>(h1, 64, b2h, b2l, 0, 4,
                                                 nullptr, stack + r * 64, RR * 64,
                                                 c2b + r * 64, zb, 64, nullptr, 1);
    }
    gate_mfma<<<9375, 256, 0, stream>>>(stack, g1h, g1l, gb1, gw2, gb2, glogit);
    final_kernel<<<NN / 4, 256, 0, stream>>>((const __hip_bfloat16*)stack, glogit,
                                             pw, pb, cw1, cb1, cw2, cb2,
                                             auxw, auxb, out);
}

// Round 5
// 3803.878 us; speedup vs baseline: 1.7703x; 1.1261x over previous
//
#include <hip/hip_runtime.h>
#include <hip/hip_bf16.h>

#define NN 100000
#define EE 1600000
#define RR 6
#define SCAN_NBLK 25   // ceil(NN/4096)

typedef __attribute__((ext_vector_type(8))) short bf16x8;
typedef __attribute__((ext_vector_type(4))) float f32x4;

__device__ inline short f2b(float x) {
    __hip_bfloat16 h = __float2bfloat16(x);
    return *reinterpret_cast<short*>(&h);
}
__device__ inline float b2f(short s) {
    __hip_bfloat16 h = *reinterpret_cast<__hip_bfloat16*>(&s);
    return __bfloat162float(h);
}

// ---------------- CSR build ----------------

__global__ __launch_bounds__(256) void zero_k(int* p, int n4) {
    int i = blockIdx.x * 256 + threadIdx.x;
    if (i < n4) ((int4*)p)[i] = make_int4(0, 0, 0, 0);
}

__global__ __launch_bounds__(256) void count_k(const int* __restrict__ src,
                                               const int* __restrict__ dst,
                                               int* __restrict__ deg, int* __restrict__ cnt) {
    int e = blockIdx.x * 256 + threadIdx.x;
    atomicAdd(&deg[src[e]], 1);
    atomicAdd(&cnt[dst[e]], 1);
}

__global__ __launch_bounds__(256) void dis_k(const int* __restrict__ deg, float* __restrict__ dis) {
    int idx = blockIdx.x * 256 + threadIdx.x;
    if (idx >= NN) return;
    int d = deg[idx];
    dis[idx] = d > 0 ? rsqrtf((float)d) : 0.f;
}

__global__ __launch_bounds__(256) void scan1(const int* __restrict__ cnt,
                                             int* __restrict__ rowp, int* __restrict__ psum) {
    int blk = blockIdx.x;
    int tid = threadIdx.x;
    int base = blk * 4096 + tid * 16;
    int vals[16];
    int run = 0;
#pragma unroll
    for (int i = 0; i < 16; i++) {
        int idx = base + i;
        int v = (idx < NN) ? cnt[idx] : 0;
        vals[i] = run;
        run += v;
    }
    int lane = tid & 63, wv = tid >> 6;
    int x = run;
#pragma unroll
    for (int d = 1; d < 64; d <<= 1) {
        int y = __shfl_up(x, d, 64);
        if (lane >= d) x += y;
    }
    __shared__ int wsum[4];
    if (lane == 63) wsum[wv] = x;
    __syncthreads();
    int woff = 0;
    for (int wi = 0; wi < wv; ++wi) woff += wsum[wi];
    int texcl = woff + x - run;
#pragma unroll
    for (int i = 0; i < 16; i++) {
        int idx = base + i;
        if (idx < NN) rowp[idx] = texcl + vals[i];
    }
    if (tid == 255) psum[blk] = woff + x;
}

__global__ void scan2(int* psum) {
    if (threadIdx.x == 0) {
        int run = 0;
        for (int b = 0; b < SCAN_NBLK; b++) {
            int t = psum[b];
            psum[b] = run;
            run += t;
        }
    }
}

__global__ __launch_bounds__(256) void scan3(int* __restrict__ rowp, int* __restrict__ cursor,
                                             const int* __restrict__ psum) {
    int blk = blockIdx.x;
    int off = psum[blk];
    int tid = threadIdx.x;
    int base = blk * 4096 + tid * 16;
#pragma unroll
    for (int i = 0; i < 16; i++) {
        int idx = base + i;
        if (idx < NN) {
            int v = rowp[idx] + off;
            rowp[idx] = v;
            cursor[idx] = v;
        }
    }
    if (blk == 0 && tid == 0) rowp[NN] = EE;
}

__global__ __launch_bounds__(256) void fill_k(const int* __restrict__ src,
                                              const int* __restrict__ dst,
                                              int* __restrict__ cursor, int* __restrict__ csr) {
    int e = blockIdx.x * 256 + threadIdx.x;
    int s = src[e], d = dst[e];
    int pos = atomicAdd(&cursor[d], 1);
    if (pos >= 0 && pos < EE) csr[pos] = s;
}

// ---------------- weight packing into MFMA B-fragment order, hi/lo bf16 ----------------
// B frag for mfma_f32_16x16x32_bf16: lane l holds B[k = s*32 + (l>>4)*8 + j][n = t*16 + (l&15)]
__global__ __launch_bounds__(256) void wpack_cheb(const float* __restrict__ W, int Kin, int KS,
                                                  short* __restrict__ bh, short* __restrict__ bl) {
    int idx = blockIdx.x * 256 + threadIdx.x;   // over R*12*KS*64
    int l = idx & 63;
    int q = idx >> 6;
    int s = q % KS; q /= KS;
    int t = q % 12; q /= 12;
    int r = q;
    if (r >= RR) return;
#pragma unroll
    for (int j = 0; j < 8; ++j) {
        int k = s * 32 + ((l >> 4) * 8) + j;
        int n = t * 16 + (l & 15);
        int g = n >> 6, jj = n & 63;
        float v = W[(((size_t)r * 3 + (g == 0 ? 0 : g)) * Kin + k) * 64 + jj];
        if (g == 0) v -= W[(((size_t)r * 3 + 2) * Kin + k) * 64 + jj];
        short hi = f2b(v);
        short lo = f2b(v - b2f(hi));
        bh[(size_t)idx * 8 + j] = hi;
        bl[(size_t)idx * 8 + j] = lo;
    }
}

// any 64x64 f32 matrix -> packed (4 ntiles x 2 ksteps), hi/lo
__global__ __launch_bounds__(256) void wpack64(const float* __restrict__ W,
                                               short* __restrict__ bh, short* __restrict__ bl) {
    int idx = blockIdx.x * 256 + threadIdx.x;   // over 4*2*64 = 512
    if (idx >= 512) return;
    int l = idx & 63;
    int s = (idx >> 6) & 1;
    int t = idx >> 7;
#pragma unroll
    for (int j = 0; j < 8; ++j) {
        int k = s * 32 + ((l >> 4) * 8) + j;
        int n = t * 16 + (l & 15);
        float v = W[k * 64 + n];
        short hi = f2b(v);
        short lo = f2b(v - b2f(hi));
        bh[(size_t)idx * 8 + j] = hi;
        bl[(size_t)idx * 8 + j] = lo;
    }
}

// ---------------- MFMA GEMM ----------------
// Tiles t=0..ntn-1 map to packed ntile nt0+t. Tiles t<fsplit -> f32 out (outf, col t*16+..),
// tiles t>=fsplit -> bf16 out (outb, col (t-fsplit)*16+..). bias/add indexed by local col.
template <int KDIM, int AF32>
__global__ __launch_bounds__(256) void gemm_mfma(const void* __restrict__ Av, int lda,
                                                 const short* __restrict__ bph,
                                                 const short* __restrict__ bplo,
                                                 int nt0, int ntn, int fsplit,
                                                 float* __restrict__ outf, int ldcf,
                                                 short* __restrict__ outb, int ldcb,
                                                 const float* __restrict__ bias,
                                                 const float* __restrict__ add, int ldadd,
                                                 const float* __restrict__ rowscale,
                                                 int do_relu) {
    constexpr int KS = KDIM / 32;
    int w = threadIdx.x >> 6, l = threadIdx.x & 63;
    int rows0 = blockIdx.x * 64 + w * 16;
    int arow = rows0 + (l & 15);
    int kbase = (l >> 4) * 8;
    bf16x8 af[KS];
    if (AF32) {
        const float* A = (const float*)Av;
#pragma unroll
        for (int s = 0; s < KS; ++s) {
            bf16x8 t = {0, 0, 0, 0, 0, 0, 0, 0};
            if (arow < NN) {
                const float* p = A + (size_t)arow * lda + s * 32 + kbase;
                float4 u0 = *(const float4*)p;
                float4 u1 = *(const float4*)(p + 4);
                t[0] = f2b(u0.x); t[1] = f2b(u0.y); t[2] = f2b(u0.z); t[3] = f2b(u0.w);
                t[4] = f2b(u1.x); t[5] = f2b(u1.y); t[6] = f2b(u1.z); t[7] = f2b(u1.w);
            }
            af[s] = t;
        }
    } else {
        const short* A = (const short*)Av;
#pragma unroll
        for (int s = 0; s < KS; ++s) {
            bf16x8 t = {0, 0, 0, 0, 0, 0, 0, 0};
            if (arow < NN) t = *(const bf16x8*)(A + (size_t)arow * lda + s * 32 + kbase);
            af[s] = t;
        }
    }
    for (int t = 0; t < ntn; ++t) {
        f32x4 acc = {0.f, 0.f, 0.f, 0.f};
        const short* bp0 = bph + (((size_t)(nt0 + t) * KS) * 64 + l) * 8;
        const short* bl0 = bplo + (((size_t)(nt0 + t) * KS) * 64 + l) * 8;
#pragma unroll
        for (int s = 0; s < KS; ++s) {
            bf16x8 bh = *(const bf16x8*)(bp0 + (size_t)s * 64 * 8);
            bf16x8 bl = *(const bf16x8*)(bl0 + (size_t)s * 64 * 8);
            acc = __builtin_amdgcn_mfma_f32_16x16x32_bf16(af[s], bh, acc, 0, 0, 0);
            acc = __builtin_amdgcn_mfma_f32_16x16x32_bf16(af[s], bl, acc, 0, 0, 0);
        }
        bool isf = (t < fsplit);
        int lcol = ((isf ? t : t - fsplit) << 4) + (l & 15);
#pragma unroll
        for (int r_ = 0; r_ < 4; ++r_) {
            int row = rows0 + (l >> 4) * 4 + r_;
            if (row >= NN) continue;
            float v = acc[r_];
            if (bias) v += bias[lcol];
            if (add) v += add[(size_t)row * ldadd + lcol];
            if (do_relu) v = fmaxf(v, 0.f);
            if (rowscale) v *= rowscale[row];
            if (isf) outf[(size_t)row * ldcf + lcol] = v;
            else outb[(size_t)row * ldcb + lcol] = f2b(v);
        }
    }
}

// ---------------- SpMM over bf16 source rows ----------------
// MID=1: outb[row,:] = bf16( y1[row,:] + 2*(-dis^2)*sum_{e} v[src,:] )
// MID=0: outf[row,:] = (-dis) * sum_{e} v[src,:]
template <int MID>
__global__ __launch_bounds__(256) void spmm_bf(const short* __restrict__ v,
                                               const float* __restrict__ y1,
                                               short* __restrict__ outb,
                                               float* __restrict__ outf,
                                               const int* __restrict__ csr,
                                               const int* __restrict__ rowp,
                                               const float* __restrict__ dis) {
    int w = threadIdx.x >> 6, lane = threadIdx.x & 63;
    int row = blockIdx.x * 4 + w;
    if (row >= NN) return;
    int s0 = max(0, rowp[row]);
    int s1 = min(EE, rowp[row + 1]);
    float acc = 0.f;
    int e = s0;
    for (; e + 4 <= s1; e += 4) {
        int i0 = csr[e], i1 = csr[e + 1], i2 = csr[e + 2], i3 = csr[e + 3];
        float a = b2f(v[(size_t)i0 * 64 + lane]);
        float b = b2f(v[(size_t)i1 * 64 + lane]);
        float c = b2f(v[(size_t)i2 * 64 + lane]);
        float d = b2f(v[(size_t)i3 * 64 + lane]);
        acc += (a + b) + (c + d);
    }
    for (; e < s1; ++e) acc += b2f(v[(size_t)csr[e] * 64 + lane]);
    float d = dis[row];
    if (MID) {
        float val = y1[(size_t)row * 64 + lane] + 2.f * (-d * d) * acc;
        outb[(size_t)row * 64 + lane] = f2b(val);
    } else {
        outf[(size_t)row * 64 + lane] = (-d) * acc;
    }
}

// ---------------- gate via MFMA: glogit = relu(stack@gw1+gb1)@gw2 + gb2 ----------------
__global__ __launch_bounds__(256) void gate_mfma(const short* __restrict__ stack,
                                                 const short* __restrict__ g1h,
                                                 const short* __restrict__ g1l,
                                                 const float* __restrict__ gb1,
                                                 const float* __restrict__ gw2,
                                                 const float* __restrict__ gb2,
                                                 float* __restrict__ glogit) {
    int w = threadIdx.x >> 6, l = threadIdx.x & 63;
    int rows0 = blockIdx.x * 64 + w * 16;      // 9375*64 == 600000 exactly
    int arow = rows0 + (l & 15);
    int kbase = (l >> 4) * 8;
    bf16x8 af[2];
#pragma unroll
    for (int s = 0; s < 2; ++s)
        af[s] = *(const bf16x8*)(stack + (size_t)arow * 64 + s * 32 + kbase);
    float p[4] = {0.f, 0.f, 0.f, 0.f};
#pragma unroll
    for (int t = 0; t < 4; ++t) {
        f32x4 acc = {0.f, 0.f, 0.f, 0.f};
#pragma unroll
        for (int s = 0; s < 2; ++s) {
            bf16x8 bh = *(const bf16x8*)(g1h + (((size_t)t * 2 + s) * 64 + l) * 8);
            bf16x8 bl = *(const bf16x8*)(g1l + (((size_t)t * 2 + s) * 64 + l) * 8);
            acc = __builtin_amdgcn_mfma_f32_16x16x32_bf16(af[s], bh, acc, 0, 0, 0);
            acc = __builtin_amdgcn_mfma_f32_16x16x32_bf16(af[s], bl, acc, 0, 0, 0);
        }
        int col = t * 16 + (l & 15);
        float b = gb1[col], w2 = gw2[col];
#pragma unroll
        for (int r_ = 0; r_ < 4; ++r_) {
            float h = fmaxf(acc[r_] + b, 0.f);
            p[r_] = fmaf(h, w2, p[r_]);
        }
    }
#pragma unroll
    for (int d = 1; d < 16; d <<= 1) {
#pragma unroll
        for (int r_ = 0; r_ < 4; ++r_) p[r_] += __shfl_xor(p[r_], d, 64);
    }
    if ((l & 15) == 0) {
        float g2 = gb2[0];
#pragma unroll
        for (int r_ = 0; r_ < 4; ++r_) glogit[rows0 + (l >> 4) * 4 + r_] = p[r_] + g2;
    }
}

// ---------------- fuse: softmax over R, h_fused (bf16), aux outputs ----------------
__global__ __launch_bounds__(256) void fuse_kernel(const short* __restrict__ stack,
                                                   const float* __restrict__ glogit,
                                                   const float* __restrict__ auxw,
                                                   const float* __restrict__ auxb,
                                                   short* __restrict__ hfused,
                                                   float* __restrict__ out) {
    __shared__ float auxws[RR * 64];
    __shared__ float auxbs[RR];
    int tid = threadIdx.x;
    for (int i = tid; i < RR * 64; i += 256) auxws[i] = auxw[i];
    if (tid < RR) auxbs[tid] = auxb[tid];
    __syncthreads();
    int w = tid >> 6, lane = tid & 63;
    int n = blockIdx.x * 4 + w;
    if (n >= NN) return;
    float gl[RR];
    float m = -1e30f;
#pragma unroll
    for (int r = 0; r < RR; r++) {
        gl[r] = glogit[(size_t)n * RR + r];
        m = fmaxf(m, gl[r]);
    }
    float ssum = 0.f;
#pragma unroll
    for (int r = 0; r < RR; r++) {
        gl[r] = __expf(gl[r] - m);
        ssum += gl[r];
    }
    float inv = 1.f / ssum;
    float hf = 0.f;
#pragma unroll
    for (int r = 0; r < RR; r++) {
        float s = b2f(stack[((size_t)n * RR + r) * 64 + lane]);
        hf = fmaf(gl[r] * inv, s, hf);
        float t = s * auxws[r * 64 + lane];
#pragma unroll
        for (int d = 32; d >= 1; d >>= 1) t += __shfl_xor(t, d, 64);
        if (lane == 0) out[NN + (size_t)n * RR + r] = t + auxbs[r];
    }
    hfused[(size_t)n * 64 + lane] = f2b(hf);
}

// ---------------- cls via MFMA: out[n] = relu(hproj@cw1+cb1)@cw2 + cb2 ----------------
__global__ __launch_bounds__(256) void cls_mfma(const short* __restrict__ hproj,
                                                const short* __restrict__ c1h,
                                                const short* __restrict__ c1l,
                                                const float* __restrict__ cb1,
                                                const float* __restrict__ cw2,
                                                const float* __restrict__ cb2,
                                                float* __restrict__ out) {
    int w = threadIdx.x >> 6, l = threadIdx.x & 63;
    int rows0 = blockIdx.x * 64 + w * 16;
    int arow = rows0 + (l & 15);
    int kbase = (l >> 4) * 8;
    bf16x8 af[2];
#pragma unroll
    for (int s = 0; s < 2; ++s) {
        bf16x8 t = {0, 0, 0, 0, 0, 0, 0, 0};
        if (arow < NN) t = *(const bf16x8*)(hproj + (size_t)arow * 64 + s * 32 + kbase);
        af[s] = t;
    }
    float p[4] = {0.f, 0.f, 0.f, 0.f};
#pragma unroll
    for (int t = 0; t < 4; ++t) {
        f32x4 acc = {0.f, 0.f, 0.f, 0.f};
#pragma unroll
        for (int s = 0; s < 2; ++s) {
            bf16x8 bh = *(const bf16x8*)(c1h + (((size_t)t * 2 + s) * 64 + l) * 8);
            bf16x8 bl = *(const bf16x8*)(c1l + (((size_t)t * 2 + s) * 64 + l) * 8);
            acc = __builtin_amdgcn_mfma_f32_16x16x32_bf16(af[s], bh, acc, 0, 0, 0);
            acc = __builtin_amdgcn_mfma_f32_16x16x32_bf16(af[s], bl, acc, 0, 0, 0);
        }
        int col = t * 16 + (l & 15);
        float b = cb1[col], w2 = cw2[col];
#pragma unroll
        for (int r_ = 0; r_ < 4; ++r_) {
            float h = fmaxf(acc[r_] + b, 0.f);
            p[r_] = fmaf(h, w2, p[r_]);
        }
    }
#pragma unroll
    for (int d = 1; d < 16; d <<= 1) {
#pragma unroll
        for (int r_ = 0; r_ < 4; ++r_) p[r_] += __shfl_xor(p[r_], d, 64);
    }
    if ((l & 15) == 0) {
        float c2 = cb2[0];
#pragma unroll
        for (int r_ = 0; r_ < 4; ++r_) {
            int row = rows0 + (l >> 4) * 4 + r_;
            if (row < NN) out[row] = p[r_] + c2;
        }
    }
}

// ---------------- host ----------------

extern "C" void kernel_launch(void* const* d_in, const int* in_sizes, int n_in,
                              void* d_out, int out_size, void* d_ws, size_t ws_size,
                              hipStream_t stream) {
    const float* x = (const float*)d_in[0];
    const int* ei = (const int*)d_in[1];
    const float* c1w = (const float*)d_in[2];
    const float* c1b = (const float*)d_in[3];
    const float* c2w = (const float*)d_in[4];
    const float* c2b = (const float*)d_in[5];
    const float* gw1 = (const float*)d_in[6];
    const float* gb1 = (const float*)d_in[7];
    const float* gw2 = (const float*)d_in[8];
    const float* gb2 = (const float*)d_in[9];
    const float* pw = (const float*)d_in[10];
    const float* pb = (const float*)d_in[11];
    const float* cw1 = (const float*)d_in[12];
    const float* cb1 = (const float*)d_in[13];
    const float* cw2 = (const float*)d_in[14];
    const float* cb2 = (const float*)d_in[15];
    const float* auxw = (const float*)d_in[16];
    const float* auxb = (const float*)d_in[17];
    float* out = (float*)d_out;

    char* wsp = (char*)d_ws;
    size_t off = 0;
    auto carve = [&](size_t bytes) -> char* {
        char* p = wsp + off;
        off += (bytes + 255) & ~(size_t)255;
        return p;
    };
    short* stack = (short*)carve((size_t)NN * RR * 64 * 2);   // bf16 [N][R][64]
    float* yb1 = (float*)carve((size_t)NN * 64 * 4);          // y1' f32; also reused as zb
    short* y2b = (short*)carve((size_t)NN * 64 * 2);          // y2' bf16; also hproj
    short* wb = (short*)carve((size_t)NN * 64 * 2);           // w' bf16
    short* h1 = (short*)carve((size_t)NN * 64 * 2);           // bf16; also hfused
    float* dis = (float*)carve((size_t)NN * 4);
    int* deg = (int*)carve((size_t)2 * NN * 4);               // deg + cnt, ONE carve
    int* cnt = deg + NN;
    int* rowp = (int*)carve((size_t)(NN + 1) * 4);
    int* cursor = (int*)carve((size_t)NN * 4);
    int* csr = (int*)carve((size_t)EE * 4);
    int* psum = (int*)carve((size_t)32 * 4);
    short* bp1h = (short*)carve((size_t)RR * 12 * 4 * 64 * 8 * 2);
    short* bp1l = (short*)carve((size_t)RR * 12 * 4 * 64 * 8 * 2);
    short* bp2h = (short*)carve((size_t)RR * 12 * 2 * 64 * 8 * 2);
    short* bp2l = (short*)carve((size_t)RR * 12 * 2 * 64 * 8 * 2);
    short* g1h = (short*)carve((size_t)512 * 8 * 2);
    short* g1l = (short*)carve((size_t)512 * 8 * 2);
    short* pwh = (short*)carve((size_t)512 * 8 * 2);
    short* pwl = (short*)carve((size_t)512 * 8 * 2);
    short* c1h = (short*)carve((size_t)512 * 8 * 2);
    short* c1l = (short*)carve((size_t)512 * 8 * 2);
    float* glogit = (float*)carve((size_t)NN * RR * 4);
    float* zb = yb1;          // alias: yb1 consumed by spmm-mid before spmm-last writes zb
    short* hfused = h1;       // alias: h1 dead after relation loop
    short* hproj = y2b;       // alias: y2b dead after relation loop
    (void)in_sizes; (void)n_in; (void)out_size;

    if (off > ws_size) return;   // guard: clean absmax-fail => ws too small

    wpack_cheb<<<72, 256, 0, stream>>>(c1w, 128, 4, bp1h, bp1l);
    wpack_cheb<<<36, 256, 0, stream>>>(c2w, 64, 2, bp2h, bp2l);
    wpack64<<<2, 256, 0, stream>>>(gw1, g1h, g1l);
    wpack64<<<2, 256, 0, stream>>>(pw, pwh, pwl);
    wpack64<<<2, 256, 0, stream>>>(cw1, c1h, c1l);

    const int GB = 1563;   // ceil(NN/64)
    for (int r = 0; r < RR; ++r) {
        const int* src = ei + (size_t)r * 2 * EE;
        const int* dst = src + EE;
        const short* b1h = bp1h + (size_t)r * 12 * 4 * 64 * 8;
        const short* b1l = bp1l + (size_t)r * 12 * 4 * 64 * 8;
        const short* b2h = bp2h + (size_t)r * 12 * 2 * 64 * 8;
        const short* b2l = bp2l + (size_t)r * 12 * 2 * 64 * 8;

        // per-relation CSR (dst-major) + dis
        zero_k<<<(2 * NN / 4 + 255) / 256, 256, 0, stream>>>(deg, 2 * NN / 4);
        count_k<<<EE / 256, 256, 0, stream>>>(src, dst, deg, cnt);
        dis_k<<<(NN + 255) / 256, 256, 0, stream>>>(deg, dis);
        scan1<<<SCAN_NBLK, 256, 0, stream>>>(cnt, rowp, psum);
        scan2<<<1, 64, 0, stream>>>(psum);
        scan3<<<SCAN_NBLK, 256, 0, stream>>>(rowp, cursor, psum);
        fill_k<<<EE / 256, 256, 0, stream>>>(src, dst, cursor, csr);

        // layer 1: tiles 4-7 -> y1' f32 (yb1), tiles 8-11 -> y2' bf16 (y2b), both dis-scaled
        gemm_mfma<128, 1><<<GB, 256, 0, stream>>>(x, 128, b1h, b1l, 4, 8, 4,
                                                  yb1, 64, y2b, 64,
                                                  nullptr, nullptr, 0, dis, 0);
        spmm_bf<1><<<NN / 4, 256, 0, stream>>>(y2b, yb1, wb, nullptr, csr, rowp, dis);
        spmm_bf<0><<<NN / 4, 256, 0, stream>>>(wb, nullptr, nullptr, zb, csr, rowp, dis);
        gemm_mfma<128, 1><<<GB, 256, 0, stream>>>(x, 128, b1h, b1l, 0, 4, 0,
                                                  nullptr, 0, h1, 64,
                                                  c1b + r * 64, zb, 64, nullptr, 1);
        // layer 2 (A = h1 bf16, K=64)
        gemm_mfma<64, 0><<<GB, 256, 0, stream>>>(h1, 64, b2h, b2l, 4, 8, 4,
                                                 yb1, 64, y2b, 64,
                                                 nullptr, nullptr, 0, dis, 0);
        spmm_bf<1><<<NN / 4, 256, 0, stream>>>(y2b, yb1, wb, nullptr, csr, rowp, dis);
        spmm_bf<0><<<NN / 4, 256, 0, stream>>>(wb, nullptr, nullptr, zb, csr, rowp, dis);
        gemm_mfma<64, 0><<<GB, 256, 0, stream>>>(h1, 64, b2h, b2l, 0, 4, 0,
                                                 nullptr, 0, stack + r * 64, RR * 64,
                                                 c2b + r * 64, zb, 64, nullptr, 1);
    }
    gate_mfma<<<9375, 256, 0, stream>>>(stack, g1h, g1l, gb1, gw2, gb2, glogit);
    fuse_kernel<<<NN / 4, 256, 0, stream>>>(stack, glogit, auxw, auxb, hfused, out);
    gemm_mfma<64, 0><<<GB, 256, 0, stream>>>(hfused, 64, pwh, pwl, 0, 4, 0,
                                             nullptr, 0, hproj, 64,
                                             pb, nullptr, 0, nullptr, 1);
    cls_mfma<<<GB, 256, 0, stream>>>(hproj, c1h, c1l, cb1, cw2, cb2, out);
}

// Round 6
// 3034.534 us; speedup vs baseline: 2.2191x; 1.2535x over previous
//
#include <hip/hip_runtime.h>
#include <hip/hip_bf16.h>

#define NN 100000
#define EE 1600000
#define RR 6
#define SCAN_NBLK 25   // ceil(NN/4096)
#define NB 98          // dst buckets of 1024 rows

typedef __attribute__((ext_vector_type(8))) short bf16x8;
typedef __attribute__((ext_vector_type(4))) float f32x4;

__device__ inline short f2b(float x) {
    __hip_bfloat16 h = __float2bfloat16(x);
    return *reinterpret_cast<short*>(&h);
}
__device__ inline float b2f(short s) {
    __hip_bfloat16 h = *reinterpret_cast<__hip_bfloat16*>(&s);
    return __bfloat162float(h);
}

// ---------------- CSR build ----------------

__global__ __launch_bounds__(256) void zero_k(int* p, int n4) {
    int i = blockIdx.x * 256 + threadIdx.x;
    if (i < n4) ((int4*)p)[i] = make_int4(0, 0, 0, 0);
}

__global__ __launch_bounds__(256) void count_k(const int* __restrict__ src,
                                               const int* __restrict__ dst,
                                               int* __restrict__ deg, int* __restrict__ cnt) {
    int e = blockIdx.x * 256 + threadIdx.x;
    atomicAdd(&deg[src[e]], 1);
    atomicAdd(&cnt[dst[e]], 1);
}

__global__ __launch_bounds__(256) void dis_k(const int* __restrict__ deg, float* __restrict__ dis) {
    int idx = blockIdx.x * 256 + threadIdx.x;
    if (idx >= NN) return;
    int d = deg[idx];
    dis[idx] = d > 0 ? rsqrtf((float)d) : 0.f;
}

__global__ __launch_bounds__(256) void scan1(const int* __restrict__ cnt,
                                             int* __restrict__ rowp, int* __restrict__ psum) {
    int blk = blockIdx.x;
    int tid = threadIdx.x;
    int base = blk * 4096 + tid * 16;
    int vals[16];
    int run = 0;
#pragma unroll
    for (int i = 0; i < 16; i++) {
        int idx = base + i;
        int v = (idx < NN) ? cnt[idx] : 0;
        vals[i] = run;
        run += v;
    }
    int lane = tid & 63, wv = tid >> 6;
    int x = run;
#pragma unroll
    for (int d = 1; d < 64; d <<= 1) {
        int y = __shfl_up(x, d, 64);
        if (lane >= d) x += y;
    }
    __shared__ int wsum[4];
    if (lane == 63) wsum[wv] = x;
    __syncthreads();
    int woff = 0;
    for (int wi = 0; wi < wv; ++wi) woff += wsum[wi];
    int texcl = woff + x - run;
#pragma unroll
    for (int i = 0; i < 16; i++) {
        int idx = base + i;
        if (idx < NN) rowp[idx] = texcl + vals[i];
    }
    if (tid == 255) psum[blk] = woff + x;
}

__global__ void scan2(int* psum) {
    if (threadIdx.x == 0) {
        int run = 0;
        for (int b = 0; b < SCAN_NBLK; b++) {
            int t = psum[b];
            psum[b] = run;
            run += t;
        }
    }
}

__global__ __launch_bounds__(256) void scan3(int* __restrict__ rowp, int* __restrict__ cursor,
                                             const int* __restrict__ psum) {
    int blk = blockIdx.x;
    int off = psum[blk];
    int tid = threadIdx.x;
    int base = blk * 4096 + tid * 16;
#pragma unroll
    for (int i = 0; i < 16; i++) {
        int idx = base + i;
        if (idx < NN) {
            int v = rowp[idx] + off;
            rowp[idx] = v;
            cursor[idx] = v;
        }
    }
    if (blk == 0 && tid == 0) rowp[NN] = EE;
}

// bcur[b] = start of bucket b's region in csr/pairs
__global__ void binit(int* __restrict__ bcur, const int* __restrict__ rowp) {
    int b = threadIdx.x;
    if (b < NB) {
        int d0 = b << 10;
        bcur[b] = rowp[d0 < NN ? d0 : NN];
    }
}

// pass A: bin edges into dst-buckets (pairs buffer), block-chunk contiguous bursts
__global__ __launch_bounds__(256) void binA(const int* __restrict__ src,
                                            const int* __restrict__ dst,
                                            int* __restrict__ bcur,
                                            int2* __restrict__ pairs) {
    __shared__ int lcnt[NB], lbase[NB], loff[NB];
    int t = threadIdx.x;
    for (int i = t; i < NB; i += 256) { lcnt[i] = 0; loff[i] = 0; }
    __syncthreads();
    int base = blockIdx.x * 4096;
#pragma unroll
    for (int i = 0; i < 16; ++i) {
        int e = base + i * 256 + t;
        if (e < EE) atomicAdd(&lcnt[dst[e] >> 10], 1);
    }
    __syncthreads();
    for (int i = t; i < NB; i += 256) {
        int c = lcnt[i];
        lbase[i] = c ? atomicAdd(&bcur[i], c) : 0;
    }
    __syncthreads();
#pragma unroll
    for (int i = 0; i < 16; ++i) {
        int e = base + i * 256 + t;
        if (e < EE) {
            int s = src[e], d = dst[e];
            int b = d >> 10;
            int p = lbase[b] + atomicAdd(&loff[b], 1);
            if (p >= 0 && p < EE) pairs[p] = make_int2(s, d);
        }
    }
}

// pass B: within-bucket exact CSR placement; blocks XCD-affine per bucket (blockIdx%8)
__global__ __launch_bounds__(256) void binB(const int2* __restrict__ pairs,
                                            const int* __restrict__ rowp,
                                            int* __restrict__ cursor,
                                            int* __restrict__ csr) {
    int lin = blockIdx.x;
    int x8 = lin & 7;
    int q = lin >> 3;
    int g = q >> 4, w = q & 15;
    int b = g * 8 + x8;
    if (b >= NB) return;
    int d0 = b << 10;
    int d1 = (b + 1) << 10;
    int bstart = rowp[d0 < NN ? d0 : NN];
    int bend = (d1 <= NN) ? rowp[d1] : EE;
    for (int e = bstart + w * 256 + threadIdx.x; e < bend; e += 16 * 256) {
        int2 pr = pairs[e];
        int pos = atomicAdd(&cursor[pr.y], 1);
        if (pos >= 0 && pos < EE) csr[pos] = pr.x;
    }
}

// ---------------- x -> bf16 once ----------------
__global__ __launch_bounds__(256) void cvt_x(const float* __restrict__ x, short* __restrict__ xb) {
    int i = blockIdx.x * 256 + threadIdx.x;   // per 8 elems
    if (i >= NN * 128 / 8) return;
    const float* p = x + (size_t)i * 8;
    float4 u0 = *(const float4*)p;
    float4 u1 = *(const float4*)(p + 4);
    bf16x8 t;
    t[0] = f2b(u0.x); t[1] = f2b(u0.y); t[2] = f2b(u0.z); t[3] = f2b(u0.w);
    t[4] = f2b(u1.x); t[5] = f2b(u1.y); t[6] = f2b(u1.z); t[7] = f2b(u1.w);
    *(bf16x8*)(xb + (size_t)i * 8) = t;
}

// ---------------- weight packing into MFMA B-fragment order, hi/lo bf16 ----------------
__global__ __launch_bounds__(256) void wpack_cheb(const float* __restrict__ W, int Kin, int KS,
                                                  short* __restrict__ bh, short* __restrict__ bl) {
    int idx = blockIdx.x * 256 + threadIdx.x;   // over R*12*KS*64
    int l = idx & 63;
    int q = idx >> 6;
    int s = q % KS; q /= KS;
    int t = q % 12; q /= 12;
    int r = q;
    if (r >= RR) return;
#pragma unroll
    for (int j = 0; j < 8; ++j) {
        int k = s * 32 + ((l >> 4) * 8) + j;
        int n = t * 16 + (l & 15);
        int g = n >> 6, jj = n & 63;
        float v = W[(((size_t)r * 3 + (g == 0 ? 0 : g)) * Kin + k) * 64 + jj];
        if (g == 0) v -= W[(((size_t)r * 3 + 2) * Kin + k) * 64 + jj];
        short hi = f2b(v);
        short lo = f2b(v - b2f(hi));
        bh[(size_t)idx * 8 + j] = hi;
        bl[(size_t)idx * 8 + j] = lo;
    }
}

__global__ __launch_bounds__(256) void wpack64(const float* __restrict__ W,
                                               short* __restrict__ bh, short* __restrict__ bl) {
    int idx = blockIdx.x * 256 + threadIdx.x;   // over 4*2*64 = 512
    if (idx >= 512) return;
    int l = idx & 63;
    int s = (idx >> 6) & 1;
    int t = idx >> 7;
#pragma unroll
    for (int j = 0; j < 8; ++j) {
        int k = s * 32 + ((l >> 4) * 8) + j;
        int n = t * 16 + (l & 15);
        float v = W[k * 64 + n];
        short hi = f2b(v);
        short lo = f2b(v - b2f(hi));
        bh[(size_t)idx * 8 + j] = hi;
        bl[(size_t)idx * 8 + j] = lo;
    }
}

// ---------------- MFMA GEMM (A bf16) ----------------
template <int KDIM>
__global__ __launch_bounds__(256) void gemm_mfma(const short* __restrict__ A, int lda,
                                                 const short* __restrict__ bph,
                                                 const short* __restrict__ bplo,
                                                 int nt0, int ntn, int fsplit,
                                                 float* __restrict__ outf, int ldcf,
                                                 short* __restrict__ outb, int ldcb,
                                                 const float* __restrict__ bias,
                                                 const float* __restrict__ add, int ldadd,
                                                 const float* __restrict__ rowscale,
                                                 int do_relu) {
    constexpr int KS = KDIM / 32;
    int w = threadIdx.x >> 6, l = threadIdx.x & 63;
    int rows0 = blockIdx.x * 64 + w * 16;
    int arow = rows0 + (l & 15);
    int kbase = (l >> 4) * 8;
    bf16x8 af[KS];
#pragma unroll
    for (int s = 0; s < KS; ++s) {
        bf16x8 t = {0, 0, 0, 0, 0, 0, 0, 0};
        if (arow < NN) t = *(const bf16x8*)(A + (size_t)arow * lda + s * 32 + kbase);
        af[s] = t;
    }
    for (int t = 0; t < ntn; ++t) {
        f32x4 acc = {0.f, 0.f, 0.f, 0.f};
        const short* bp0 = bph + (((size_t)(nt0 + t) * KS) * 64 + l) * 8;
        const short* bl0 = bplo + (((size_t)(nt0 + t) * KS) * 64 + l) * 8;
#pragma unroll
        for (int s = 0; s < KS; ++s) {
            bf16x8 bh = *(const bf16x8*)(bp0 + (size_t)s * 64 * 8);
            bf16x8 bl = *(const bf16x8*)(bl0 + (size_t)s * 64 * 8);
            acc = __builtin_amdgcn_mfma_f32_16x16x32_bf16(af[s], bh, acc, 0, 0, 0);
            acc = __builtin_amdgcn_mfma_f32_16x16x32_bf16(af[s], bl, acc, 0, 0, 0);
        }
        bool isf = (t < fsplit);
        int lcol = ((isf ? t : t - fsplit) << 4) + (l & 15);
#pragma unroll
        for (int r_ = 0; r_ < 4; ++r_) {
            int row = rows0 + (l >> 4) * 4 + r_;
            if (row >= NN) continue;
            float v = acc[r_];
            if (bias) v += bias[lcol];
            if (add) v += add[(size_t)row * ldadd + lcol];
            if (do_relu) v = fmaxf(v, 0.f);
            if (rowscale) v *= rowscale[row];
            if (isf) outf[(size_t)row * ldcf + lcol] = v;
            else outb[(size_t)row * ldcb + lcol] = f2b(v);
        }
    }
}

// ---------------- SpMM over bf16 source rows: half-wave = one row, lane = 2 feats ----------------
// MID=1: outb[row,:] = bf16( y1[row,:] - 2*dis^2*sum v[src,:] )
// MID=0: outf[row,:] = -dis * sum v[src,:]
template <int MID>
__global__ __launch_bounds__(256) void spmm_bf(const short* __restrict__ v,
                                               const float* __restrict__ y1,
                                               short* __restrict__ outb,
                                               float* __restrict__ outf,
                                               const int* __restrict__ csr,
                                               const int* __restrict__ rowp,
                                               const float* __restrict__ dis) {
    int tid = threadIdx.x;
    int wv = tid >> 6, l = tid & 63;
    int h = l >> 5, fl = l & 31;
    int row = blockIdx.x * 8 + wv * 2 + h;   // NN divisible by 8
    int s0 = max(0, rowp[row]);
    int s1 = min(EE, rowp[row + 1]);
    float a0 = 0.f, a1 = 0.f;
    int e = s0;
    for (; e + 8 <= s1; e += 8) {
        int idx[8];
#pragma unroll
        for (int i = 0; i < 8; ++i) idx[i] = csr[e + i];
        unsigned u[8];
#pragma unroll
        for (int i = 0; i < 8; ++i)
            u[i] = *(const unsigned*)(v + (size_t)idx[i] * 64 + fl * 2);
#pragma unroll
        for (int i = 0; i < 8; ++i) {
            a0 += __uint_as_float(u[i] << 16);
            a1 += __uint_as_float(u[i] & 0xffff0000u);
        }
    }
    for (; e < s1; ++e) {
        unsigned u = *(const unsigned*)(v + (size_t)csr[e] * 64 + fl * 2);
        a0 += __uint_as_float(u << 16);
        a1 += __uint_as_float(u & 0xffff0000u);
    }
    float d = dis[row];
    if (MID) {
        float2 y = *(const float2*)(y1 + (size_t)row * 64 + fl * 2);
        float m = -2.f * d * d;
        float v0 = y.x + m * a0;
        float v1 = y.y + m * a1;
        unsigned o = (unsigned)(unsigned short)f2b(v0) | ((unsigned)(unsigned short)f2b(v1) << 16);
        *(unsigned*)(outb + (size_t)row * 64 + fl * 2) = o;
    } else {
        float2 o = make_float2(-d * a0, -d * a1);
        *(float2*)(outf + (size_t)row * 64 + fl * 2) = o;
    }
}

// ---------------- gate via MFMA ----------------
__global__ __launch_bounds__(256) void gate_mfma(const short* __restrict__ stack,
                                                 const short* __restrict__ g1h,
                                                 const short* __restrict__ g1l,
                                                 const float* __restrict__ gb1,
                                                 const float* __restrict__ gw2,
                                                 const float* __restrict__ gb2,
                                                 float* __restrict__ glogit) {
    int w = threadIdx.x >> 6, l = threadIdx.x & 63;
    int rows0 = blockIdx.x * 64 + w * 16;      // 9375*64 == 600000 exactly
    int arow = rows0 + (l & 15);
    int kbase = (l >> 4) * 8;
    bf16x8 af[2];
#pragma unroll
    for (int s = 0; s < 2; ++s)
        af[s] = *(const bf16x8*)(stack + (size_t)arow * 64 + s * 32 + kbase);
    float p[4] = {0.f, 0.f, 0.f, 0.f};
#pragma unroll
    for (int t = 0; t < 4; ++t) {
        f32x4 acc = {0.f, 0.f, 0.f, 0.f};
#pragma unroll
        for (int s = 0; s < 2; ++s) {
            bf16x8 bh = *(const bf16x8*)(g1h + (((size_t)t * 2 + s) * 64 + l) * 8);
            bf16x8 bl = *(const bf16x8*)(g1l + (((size_t)t * 2 + s) * 64 + l) * 8);
            acc = __builtin_amdgcn_mfma_f32_16x16x32_bf16(af[s], bh, acc, 0, 0, 0);
            acc = __builtin_amdgcn_mfma_f32_16x16x32_bf16(af[s], bl, acc, 0, 0, 0);
        }
        int col = t * 16 + (l & 15);
        float b = gb1[col], w2 = gw2[col];
#pragma unroll
        for (int r_ = 0; r_ < 4; ++r_) {
            float h = fmaxf(acc[r_] + b, 0.f);
            p[r_] = fmaf(h, w2, p[r_]);
        }
    }
#pragma unroll
    for (int d = 1; d < 16; d <<= 1) {
#pragma unroll
        for (int r_ = 0; r_ < 4; ++r_) p[r_] += __shfl_xor(p[r_], d, 64);
    }
    if ((l & 15) == 0) {
        float g2 = gb2[0];
#pragma unroll
        for (int r_ = 0; r_ < 4; ++r_) glogit[rows0 + (l >> 4) * 4 + r_] = p[r_] + g2;
    }
}

// ---------------- fuse: softmax over R, h_fused (bf16), aux outputs ----------------
__global__ __launch_bounds__(256) void fuse_kernel(const short* __restrict__ stack,
                                                   const float* __restrict__ glogit,
                                                   const float* __restrict__ auxw,
                                                   const float* __restrict__ auxb,
                                                   short* __restrict__ hfused,
                                                   float* __restrict__ out) {
    __shared__ float auxws[RR * 64];
    __shared__ float auxbs[RR];
    int tid = threadIdx.x;
    for (int i = tid; i < RR * 64; i += 256) auxws[i] = auxw[i];
    if (tid < RR) auxbs[tid] = auxb[tid];
    __syncthreads();
    int w = tid >> 6, lane = tid & 63;
    int n = blockIdx.x * 4 + w;
    if (n >= NN) return;
    float gl[RR];
    float m = -1e30f;
#pragma unroll
    for (int r = 0; r < RR; r++) {
        gl[r] = glogit[(size_t)n * RR + r];
        m = fmaxf(m, gl[r]);
    }
    float ssum = 0.f;
#pragma unroll
    for (int r = 0; r < RR; r++) {
        gl[r] = __expf(gl[r] - m);
        ssum += gl[r];
    }
    float inv = 1.f / ssum;
    float hf = 0.f;
#pragma unroll
    for (int r = 0; r < RR; r++) {
        float s = b2f(stack[((size_t)n * RR + r) * 64 + lane]);
        hf = fmaf(gl[r] * inv, s, hf);
        float t = s * auxws[r * 64 + lane];
#pragma unroll
        for (int d = 32; d >= 1; d >>= 1) t += __shfl_xor(t, d, 64);
        if (lane == 0) out[NN + (size_t)n * RR + r] = t + auxbs[r];
    }
    hfused[(size_t)n * 64 + lane] = f2b(hf);
}

// ---------------- cls via MFMA ----------------
__global__ __launch_bounds__(256) void cls_mfma(const short* __restrict__ hproj,
                                                const short* __restrict__ c1h,
                                                const short* __restrict__ c1l,
                                                const float* __restrict__ cb1,
                                                const float* __restrict__ cw2,
                                                const float* __restrict__ cb2,
                                                float* __restrict__ out) {
    int w = threadIdx.x >> 6, l = threadIdx.x & 63;
    int rows0 = blockIdx.x * 64 + w * 16;
    int arow = rows0 + (l & 15);
    int kbase = (l >> 4) * 8;
    bf16x8 af[2];
#pragma unroll
    for (int s = 0; s < 2; ++s) {
        bf16x8 t = {0, 0, 0, 0, 0, 0, 0, 0};
        if (arow < NN) t = *(const bf16x8*)(hproj + (size_t)arow * 64 + s * 32 + kbase);
        af[s] = t;
    }
    float p[4] = {0.f, 0.f, 0.f, 0.f};
#pragma unroll
    for (int t = 0; t < 4; ++t) {
        f32x4 acc = {0.f, 0.f, 0.f, 0.f};
#pragma unroll
        for (int s = 0; s < 2; ++s) {
            bf16x8 bh = *(const bf16x8*)(c1h + (((size_t)t * 2 + s) * 64 + l) * 8);
            bf16x8 bl = *(const bf16x8*)(c1l + (((size_t)t * 2 + s) * 64 + l) * 8);
            acc = __builtin_amdgcn_mfma_f32_16x16x32_bf16(af[s], bh, acc, 0, 0, 0);
            acc = __builtin_amdgcn_mfma_f32_16x16x32_bf16(af[s], bl, acc, 0, 0, 0);
        }
        int col = t * 16 + (l & 15);
        float b = cb1[col], w2 = cw2[col];
#pragma unroll
        for (int r_ = 0; r_ < 4; ++r_) {
            float h = fmaxf(acc[r_] + b, 0.f);
            p[r_] = fmaf(h, w2, p[r_]);
        }
    }
#pragma unroll
    for (int d = 1; d < 16; d <<= 1) {
#pragma unroll
        for (int r_ = 0; r_ < 4; ++r_) p[r_] += __shfl_xor(p[r_], d, 64);
    }
    if ((l & 15) == 0) {
        float c2 = cb2[0];
#pragma unroll
        for (int r_ = 0; r_ < 4; ++r_) {
            int row = rows0 + (l >> 4) * 4 + r_;
            if (row < NN) out[row] = p[r_] + c2;
        }
    }
}

// ---------------- host ----------------

extern "C" void kernel_launch(void* const* d_in, const int* in_sizes, int n_in,
                              void* d_out, int out_size, void* d_ws, size_t ws_size,
                              hipStream_t stream) {
    const float* x = (const float*)d_in[0];
    const int* ei = (const int*)d_in[1];
    const float* c1w = (const float*)d_in[2];
    const float* c1b = (const float*)d_in[3];
    const float* c2w = (const float*)d_in[4];
    const float* c2b = (const float*)d_in[5];
    const float* gw1 = (const float*)d_in[6];
    const float* gb1 = (const float*)d_in[7];
    const float* gw2 = (const float*)d_in[8];
    const float* gb2 = (const float*)d_in[9];
    const float* pw = (const float*)d_in[10];
    const float* pb = (const float*)d_in[11];
    const float* cw1 = (const float*)d_in[12];
    const float* cb1 = (const float*)d_in[13];
    const float* cw2 = (const float*)d_in[14];
    const float* cb2 = (const float*)d_in[15];
    const float* auxw = (const float*)d_in[16];
    const float* auxb = (const float*)d_in[17];
    float* out = (float*)d_out;

    char* wsp = (char*)d_ws;
    size_t off = 0;
    auto carve = [&](size_t bytes) -> char* {
        char* p = wsp + off;
        off += (bytes + 255) & ~(size_t)255;
        return p;
    };
    short* stack = (short*)carve((size_t)NN * RR * 64 * 2);   // bf16 [N][R][64]
    float* yb1 = (float*)carve((size_t)NN * 64 * 4);          // y1' f32; aliases zb & pairs
    short* y2b = (short*)carve((size_t)NN * 64 * 2);          // y2' bf16; also hproj
    short* wb = (short*)carve((size_t)NN * 64 * 2);           // w' bf16
    short* h1 = (short*)carve((size_t)NN * 64 * 2);           // bf16; also hfused
    short* xb = (short*)carve((size_t)NN * 128 * 2);          // x as bf16
    float* dis = (float*)carve((size_t)NN * 4);
    int* deg = (int*)carve((size_t)2 * NN * 4);               // deg + cnt, ONE carve
    int* cnt = deg + NN;
    int* rowp = (int*)carve((size_t)(NN + 1) * 4);
    int* cursor = (int*)carve((size_t)NN * 4);
    int* csr = (int*)carve((size_t)EE * 4);
    int* psum = (int*)carve((size_t)32 * 4);
    int* bcur = (int*)carve((size_t)NB * 4);
    short* bp1h = (short*)carve((size_t)RR * 12 * 4 * 64 * 8 * 2);
    short* bp1l = (short*)carve((size_t)RR * 12 * 4 * 64 * 8 * 2);
    short* bp2h = (short*)carve((size_t)RR * 12 * 2 * 64 * 8 * 2);
    short* bp2l = (short*)carve((size_t)RR * 12 * 2 * 64 * 8 * 2);
    short* g1h = (short*)carve((size_t)512 * 8 * 2);
    short* g1l = (short*)carve((size_t)512 * 8 * 2);
    short* pwh = (short*)carve((size_t)512 * 8 * 2);
    short* pwl = (short*)carve((size_t)512 * 8 * 2);
    short* c1h = (short*)carve((size_t)512 * 8 * 2);
    short* c1l = (short*)carve((size_t)512 * 8 * 2);
    float* glogit = (float*)carve((size_t)NN * RR * 4);
    float* zb = yb1;          // alias: y1' consumed by spmm-mid before spmm-last writes zb
    int2* pairs = (int2*)yb1; // alias: CSR build precedes gemm writes of yb1 each relation
    short* hfused = h1;       // alias: h1 dead after relation loop
    short* hproj = y2b;       // alias: y2b dead after relation loop
    (void)in_sizes; (void)n_in; (void)out_size;

    if (off > ws_size) return;   // guard: clean absmax-fail => ws too small

    cvt_x<<<(NN * 128 / 8 + 255) / 256, 256, 0, stream>>>(x, xb);
    wpack_cheb<<<72, 256, 0, stream>>>(c1w, 128, 4, bp1h, bp1l);
    wpack_cheb<<<36, 256, 0, stream>>>(c2w, 64, 2, bp2h, bp2l);
    wpack64<<<2, 256, 0, stream>>>(gw1, g1h, g1l);
    wpack64<<<2, 256, 0, stream>>>(pw, pwh, pwl);
    wpack64<<<2, 256, 0, stream>>>(cw1, c1h, c1l);

    const int GB = 1563;   // ceil(NN/64)
    for (int r = 0; r < RR; ++r) {
        const int* src = ei + (size_t)r * 2 * EE;
        const int* dst = src + EE;
        const short* b1h = bp1h + (size_t)r * 12 * 4 * 64 * 8;
        const short* b1l = bp1l + (size_t)r * 12 * 4 * 64 * 8;
        const short* b2h = bp2h + (size_t)r * 12 * 2 * 64 * 8;
        const short* b2l = bp2l + (size_t)r * 12 * 2 * 64 * 8;

        // per-relation CSR (dst-major, bucket-binned 2-pass scatter) + dis
        zero_k<<<(2 * NN / 4 + 255) / 256, 256, 0, stream>>>(deg, 2 * NN / 4);
        count_k<<<EE / 256, 256, 0, stream>>>(src, dst, deg, cnt);
        dis_k<<<(NN + 255) / 256, 256, 0, stream>>>(deg, dis);
        scan1<<<SCAN_NBLK, 256, 0, stream>>>(cnt, rowp, psum);
        scan2<<<1, 64, 0, stream>>>(psum);
        scan3<<<SCAN_NBLK, 256, 0, stream>>>(rowp, cursor, psum);
        binit<<<1, 128, 0, stream>>>(bcur, rowp);
        binA<<<(EE + 4095) / 4096, 256, 0, stream>>>(src, dst, bcur, pairs);
        binB<<<((NB + 7) / 8) * 16 * 8, 256, 0, stream>>>(pairs, rowp, cursor, csr);

        // layer 1: tiles 4-7 -> y1' f32 (yb1), tiles 8-11 -> y2' bf16 (y2b), both dis-scaled
        gemm_mfma<128><<<GB, 256, 0, stream>>>(xb, 128, b1h, b1l, 4, 8, 4,
                                               yb1, 64, y2b, 64,
                                               nullptr, nullptr, 0, dis, 0);
        spmm_bf<1><<<NN / 8, 256, 0, stream>>>(y2b, yb1, wb, nullptr, csr, rowp, dis);
        spmm_bf<0><<<NN / 8, 256, 0, stream>>>(wb, nullptr, nullptr, zb, csr, rowp, dis);
        gemm_mfma<128><<<GB, 256, 0, stream>>>(xb, 128, b1h, b1l, 0, 4, 0,
                                               nullptr, 0, h1, 64,
                                               c1b + r * 64, zb, 64, nullptr, 1);
        // layer 2 (A = h1 bf16, K=64)
        gemm_mfma<64><<<GB, 256, 0, stream>>>(h1, 64, b2h, b2l, 4, 8, 4,
                                              yb1, 64, y2b, 64,
                                              nullptr, nullptr, 0, dis, 0);
        spmm_bf<1><<<NN / 8, 256, 0, stream>>>(y2b, yb1, wb, nullptr, csr, rowp, dis);
        spmm_bf<0><<<NN / 8, 256, 0, stream>>>(wb, nullptr, nullptr, zb, csr, rowp, dis);
        gemm_mfma<64><<<GB, 256, 0, stream>>>(h1, 64, b2h, b2l, 0, 4, 0,
                                              nullptr, 0, stack + r * 64, RR * 64,
                                              c2b + r * 64, zb, 64, nullptr, 1);
    }
    gate_mfma<<<9375, 256, 0, stream>>>(stack, g1h, g1l, gb1, gw2, gb2, glogit);
    fuse_kernel<<<NN / 4, 256, 0, stream>>>(stack, glogit, auxw, auxb, hfused, out);
    gemm_mfma<64><<<GB, 256, 0, stream>>>(hfused, 64, pwh, pwl, 0, 4, 0,
                                          nullptr, 0, hproj, 64,
                                          pb, nullptr, 0, nullptr, 1);
    cls_mfma<<<GB, 256, 0, stream>>>(hproj, c1h, c1l, cb1, cw2, cb2, out);
}

// Round 7
// 2404.639 us; speedup vs baseline: 2.8004x; 1.2620x over previous
//
#include <hip/hip_runtime.h>
#include <hip/hip_bf16.h>

#define NN 100000
#define EE 1600000
#define RR 6
#define NB 98          // node buckets of 1024

typedef __attribute__((ext_vector_type(8))) short bf16x8;
typedef __attribute__((ext_vector_type(4))) float f32x4;

__device__ inline short f2b(float x) {
    __hip_bfloat16 h = __float2bfloat16(x);
    return *reinterpret_cast<short*>(&h);
}
__device__ inline float b2f(short s) {
    __hip_bfloat16 h = *reinterpret_cast<__hip_bfloat16*>(&s);
    return __bfloat162float(h);
}

// ---------------- CSR build: 2-level bucket sort, LDS-only per-node atomics ----------------

__global__ void zero_bcnt(int* __restrict__ bcnt) {
    int i = threadIdx.x;
    if (i < 2 * NB) bcnt[i] = 0;
}

__global__ __launch_bounds__(256) void bin_count(const int* __restrict__ src,
                                                 const int* __restrict__ dst,
                                                 int* __restrict__ bcntD,
                                                 int* __restrict__ bcntS) {
    __shared__ int lcD[NB], lcS[NB];
    int t = threadIdx.x;
    for (int i = t; i < NB; i += 256) { lcD[i] = 0; lcS[i] = 0; }
    __syncthreads();
    int base = blockIdx.x * 4096;
#pragma unroll
    for (int i = 0; i < 16; ++i) {
        int e = base + i * 256 + t;
        if (e < EE) {
            atomicAdd(&lcD[dst[e] >> 10], 1);
            atomicAdd(&lcS[src[e] >> 10], 1);
        }
    }
    __syncthreads();
    for (int i = t; i < NB; i += 256) {
        if (lcD[i]) atomicAdd(&bcntD[i], lcD[i]);
        if (lcS[i]) atomicAdd(&bcntS[i], lcS[i]);
    }
}

__global__ void bin_scan(const int* __restrict__ bcntD, const int* __restrict__ bcntS,
                         int* __restrict__ bbaseD, int* __restrict__ bcurD,
                         int* __restrict__ bbaseS, int* __restrict__ bcurS,
                         int* __restrict__ rowp) {
    if (threadIdx.x == 0) {
        int run = 0;
        for (int i = 0; i < NB; ++i) { bbaseD[i] = run; bcurD[i] = run; run += bcntD[i]; }
        bbaseD[NB] = run;
        run = 0;
        for (int i = 0; i < NB; ++i) { bbaseS[i] = run; bcurS[i] = run; run += bcntS[i]; }
        bbaseS[NB] = run;
        rowp[NN] = EE;
    }
}

__global__ __launch_bounds__(256) void bin_scatter(const int* __restrict__ src,
                                                   const int* __restrict__ dst,
                                                   int* __restrict__ bcurD,
                                                   int* __restrict__ bcurS,
                                                   unsigned* __restrict__ pairs,
                                                   unsigned short* __restrict__ srcs) {
    __shared__ int lcD[NB], lbD[NB], loD[NB];
    __shared__ int lcS[NB], lbS[NB], loS[NB];
    int t = threadIdx.x;
    for (int i = t; i < NB; i += 256) { lcD[i] = 0; loD[i] = 0; lcS[i] = 0; loS[i] = 0; }
    __syncthreads();
    int base = blockIdx.x * 4096;
#pragma unroll
    for (int i = 0; i < 16; ++i) {
        int e = base + i * 256 + t;
        if (e < EE) {
            atomicAdd(&lcD[dst[e] >> 10], 1);
            atomicAdd(&lcS[src[e] >> 10], 1);
        }
    }
    __syncthreads();
    for (int i = t; i < NB; i += 256) {
        lbD[i] = lcD[i] ? atomicAdd(&bcurD[i], lcD[i]) : 0;
        lbS[i] = lcS[i] ? atomicAdd(&bcurS[i], lcS[i]) : 0;
    }
    __syncthreads();
#pragma unroll
    for (int i = 0; i < 16; ++i) {
        int e = base + i * 256 + t;
        if (e < EE) {
            int s = src[e], d = dst[e];
            int bD = d >> 10, bS = s >> 10;
            int pD = lbD[bD] + atomicAdd(&loD[bD], 1);
            if (pD >= 0 && pD < EE) pairs[pD] = ((unsigned)s << 10) | (unsigned)(d & 1023);
            int pS = lbS[bS] + atomicAdd(&loS[bS], 1);
            if (pS >= 0 && pS < EE) srcs[pS] = (unsigned short)(s & 1023);
        }
    }
}

// one block per dst-bucket: LDS hist(1024) -> scan -> rowp segment -> LDS-cursor csr scatter
__global__ __launch_bounds__(256) void csr_build(const unsigned* __restrict__ pairs,
                                                 const int* __restrict__ bbase,
                                                 int* __restrict__ rowp,
                                                 int* __restrict__ csr) {
    __shared__ int hist[1024];
    __shared__ int wsums[4];
    int b = blockIdx.x;
    int t = threadIdx.x;
    int p0 = bbase[b], p1 = bbase[b + 1];
    for (int i = t; i < 1024; i += 256) hist[i] = 0;
    __syncthreads();
    for (int e = p0 + t; e < p1; e += 256)
        atomicAdd(&hist[pairs[e] & 1023], 1);
    __syncthreads();
    int h0 = hist[t * 4], h1 = hist[t * 4 + 1], h2 = hist[t * 4 + 2], h3 = hist[t * 4 + 3];
    int tsum = h0 + h1 + h2 + h3;
    int lane = t & 63, wv = t >> 6;
    int x = tsum;
#pragma unroll
    for (int d = 1; d < 64; d <<= 1) {
        int y = __shfl_up(x, d, 64);
        if (lane >= d) x += y;
    }
    if (lane == 63) wsums[wv] = x;
    __syncthreads();
    int woff = 0;
    for (int wi = 0; wi < wv; ++wi) woff += wsums[wi];
    int e0 = woff + x - tsum;          // exclusive prefix of this thread's 4 rows
    int e1 = e0 + h0, e2 = e1 + h1, e3 = e2 + h2;
    int r0 = b * 1024 + t * 4;
    if (r0 + 0 < NN) rowp[r0 + 0] = p0 + e0;
    if (r0 + 1 < NN) rowp[r0 + 1] = p0 + e1;
    if (r0 + 2 < NN) rowp[r0 + 2] = p0 + e2;
    if (r0 + 3 < NN) rowp[r0 + 3] = p0 + e3;
    __syncthreads();
    hist[t * 4] = e0; hist[t * 4 + 1] = e1; hist[t * 4 + 2] = e2; hist[t * 4 + 3] = e3;
    __syncthreads();
    for (int e = p0 + t; e < p1; e += 256) {
        unsigned pr = pairs[e];
        int pos = p0 + atomicAdd(&hist[pr & 1023], 1);
        if (pos >= 0 && pos < EE) csr[pos] = (int)(pr >> 10);
    }
}

// one block per src-bucket: LDS hist -> dis = rsqrt(deg)
__global__ __launch_bounds__(256) void deg_dis(const unsigned short* __restrict__ srcs,
                                               const int* __restrict__ sbase,
                                               float* __restrict__ dis) {
    __shared__ int hist[1024];
    int b = blockIdx.x, t = threadIdx.x;
    int p0 = sbase[b], p1 = sbase[b + 1];
    for (int i = t; i < 1024; i += 256) hist[i] = 0;
    __syncthreads();
    for (int e = p0 + t; e < p1; e += 256)
        atomicAdd(&hist[srcs[e]], 1);
    __syncthreads();
    for (int i = t; i < 1024; i += 256) {
        int node = b * 1024 + i;
        if (node < NN) {
            int d = hist[i];
            dis[node] = d > 0 ? rsqrtf((float)d) : 0.f;
        }
    }
}

// ---------------- x -> bf16 once ----------------
__global__ __launch_bounds__(256) void cvt_x(const float* __restrict__ x, short* __restrict__ xb) {
    int i = blockIdx.x * 256 + threadIdx.x;   // per 8 elems
    if (i >= NN * 128 / 8) return;
    const float* p = x + (size_t)i * 8;
    float4 u0 = *(const float4*)p;
    float4 u1 = *(const float4*)(p + 4);
    bf16x8 t;
    t[0] = f2b(u0.x); t[1] = f2b(u0.y); t[2] = f2b(u0.z); t[3] = f2b(u0.w);
    t[4] = f2b(u1.x); t[5] = f2b(u1.y); t[6] = f2b(u1.z); t[7] = f2b(u1.w);
    *(bf16x8*)(xb + (size_t)i * 8) = t;
}

// ---------------- weight packing into MFMA B-fragment order, hi/lo bf16 ----------------
__global__ __launch_bounds__(256) void wpack_cheb(const float* __restrict__ W, int Kin, int KS,
                                                  short* __restrict__ bh, short* __restrict__ bl) {
    int idx = blockIdx.x * 256 + threadIdx.x;   // over R*12*KS*64
    int l = idx & 63;
    int q = idx >> 6;
    int s = q % KS; q /= KS;
    int t = q % 12; q /= 12;
    int r = q;
    if (r >= RR) return;
#pragma unroll
    for (int j = 0; j < 8; ++j) {
        int k = s * 32 + ((l >> 4) * 8) + j;
        int n = t * 16 + (l & 15);
        int g = n >> 6, jj = n & 63;
        float v = W[(((size_t)r * 3 + (g == 0 ? 0 : g)) * Kin + k) * 64 + jj];
        if (g == 0) v -= W[(((size_t)r * 3 + 2) * Kin + k) * 64 + jj];
        short hi = f2b(v);
        short lo = f2b(v - b2f(hi));
        bh[(size_t)idx * 8 + j] = hi;
        bl[(size_t)idx * 8 + j] = lo;
    }
}

__global__ __launch_bounds__(256) void wpack64(const float* __restrict__ W,
                                               short* __restrict__ bh, short* __restrict__ bl) {
    int idx = blockIdx.x * 256 + threadIdx.x;   // over 4*2*64 = 512
    if (idx >= 512) return;
    int l = idx & 63;
    int s = (idx >> 6) & 1;
    int t = idx >> 7;
#pragma unroll
    for (int j = 0; j < 8; ++j) {
        int k = s * 32 + ((l >> 4) * 8) + j;
        int n = t * 16 + (l & 15);
        float v = W[k * 64 + n];
        short hi = f2b(v);
        short lo = f2b(v - b2f(hi));
        bh[(size_t)idx * 8 + j] = hi;
        bl[(size_t)idx * 8 + j] = lo;
    }
}

// ---------------- MFMA GEMM (A bf16) ----------------
template <int KDIM>
__global__ __launch_bounds__(256) void gemm_mfma(const short* __restrict__ A, int lda,
                                                 const short* __restrict__ bph,
                                                 const short* __restrict__ bplo,
                                                 int nt0, int ntn, int fsplit,
                                                 float* __restrict__ outf, int ldcf,
                                                 short* __restrict__ outb, int ldcb,
                                                 const float* __restrict__ bias,
                                                 const float* __restrict__ add, int ldadd,
                                                 const float* __restrict__ rowscale,
                                                 int do_relu) {
    constexpr int KS = KDIM / 32;
    int w = threadIdx.x >> 6, l = threadIdx.x & 63;
    int rows0 = blockIdx.x * 64 + w * 16;
    int arow = rows0 + (l & 15);
    int kbase = (l >> 4) * 8;
    bf16x8 af[KS];
#pragma unroll
    for (int s = 0; s < KS; ++s) {
        bf16x8 t = {0, 0, 0, 0, 0, 0, 0, 0};
        if (arow < NN) t = *(const bf16x8*)(A + (size_t)arow * lda + s * 32 + kbase);
        af[s] = t;
    }
    for (int t = 0; t < ntn; ++t) {
        f32x4 acc = {0.f, 0.f, 0.f, 0.f};
        const short* bp0 = bph + (((size_t)(nt0 + t) * KS) * 64 + l) * 8;
        const short* bl0 = bplo + (((size_t)(nt0 + t) * KS) * 64 + l) * 8;
#pragma unroll
        for (int s = 0; s < KS; ++s) {
            bf16x8 bh = *(const bf16x8*)(bp0 + (size_t)s * 64 * 8);
            bf16x8 bl = *(const bf16x8*)(bl0 + (size_t)s * 64 * 8);
            acc = __builtin_amdgcn_mfma_f32_16x16x32_bf16(af[s], bh, acc, 0, 0, 0);
            acc = __builtin_amdgcn_mfma_f32_16x16x32_bf16(af[s], bl, acc, 0, 0, 0);
        }
        bool isf = (t < fsplit);
        int lcol = ((isf ? t : t - fsplit) << 4) + (l & 15);
#pragma unroll
        for (int r_ = 0; r_ < 4; ++r_) {
            int row = rows0 + (l >> 4) * 4 + r_;
            if (row >= NN) continue;
            float v = acc[r_];
            if (bias) v += bias[lcol];
            if (add) v += add[(size_t)row * ldadd + lcol];
            if (do_relu) v = fmaxf(v, 0.f);
            if (rowscale) v *= rowscale[row];
            if (isf) outf[(size_t)row * ldcf + lcol] = v;
            else outb[(size_t)row * ldcb + lcol] = f2b(v);
        }
    }
}

// ---------------- SpMM over bf16 source rows: half-wave = one row, lane = 2 feats ----------------
template <int MID>
__global__ __launch_bounds__(256) void spmm_bf(const short* __restrict__ v,
                                               const float* __restrict__ y1,
                                               short* __restrict__ outb,
                                               float* __restrict__ outf,
                                               const int* __restrict__ csr,
                                               const int* __restrict__ rowp,
                                               const float* __restrict__ dis) {
    int tid = threadIdx.x;
    int wv = tid >> 6, l = tid & 63;
    int h = l >> 5, fl = l & 31;
    int row = blockIdx.x * 8 + wv * 2 + h;   // NN divisible by 8
    int s0 = max(0, rowp[row]);
    int s1 = min(EE, rowp[row + 1]);
    float a0 = 0.f, a1 = 0.f;
    int e = s0;
    for (; e + 8 <= s1; e += 8) {
        int idx[8];
#pragma unroll
        for (int i = 0; i < 8; ++i) idx[i] = csr[e + i];
        unsigned u[8];
#pragma unroll
        for (int i = 0; i < 8; ++i)
            u[i] = *(const unsigned*)(v + (size_t)idx[i] * 64 + fl * 2);
#pragma unroll
        for (int i = 0; i < 8; ++i) {
            a0 += __uint_as_float(u[i] << 16);
            a1 += __uint_as_float(u[i] & 0xffff0000u);
        }
    }
    for (; e < s1; ++e) {
        unsigned u = *(const unsigned*)(v + (size_t)csr[e] * 64 + fl * 2);
        a0 += __uint_as_float(u << 16);
        a1 += __uint_as_float(u & 0xffff0000u);
    }
    float d = dis[row];
    if (MID) {
        float2 y = *(const float2*)(y1 + (size_t)row * 64 + fl * 2);
        float m = -2.f * d * d;
        float v0 = y.x + m * a0;
        float v1 = y.y + m * a1;
        unsigned o = (unsigned)(unsigned short)f2b(v0) | ((unsigned)(unsigned short)f2b(v1) << 16);
        *(unsigned*)(outb + (size_t)row * 64 + fl * 2) = o;
    } else {
        float2 o = make_float2(-d * a0, -d * a1);
        *(float2*)(outf + (size_t)row * 64 + fl * 2) = o;
    }
}

// ---------------- gate via MFMA ----------------
__global__ __launch_bounds__(256) void gate_mfma(const short* __restrict__ stack,
                                                 const short* __restrict__ g1h,
                                                 const short* __restrict__ g1l,
                                                 const float* __restrict__ gb1,
                                                 const float* __restrict__ gw2,
                                                 const float* __restrict__ gb2,
                                                 float* __restrict__ glogit) {
    int w = threadIdx.x >> 6, l = threadIdx.x & 63;
    int rows0 = blockIdx.x * 64 + w * 16;      // 9375*64 == 600000 exactly
    int arow = rows0 + (l & 15);
    int kbase = (l >> 4) * 8;
    bf16x8 af[2];
#pragma unroll
    for (int s = 0; s < 2; ++s)
        af[s] = *(const bf16x8*)(stack + (size_t)arow * 64 + s * 32 + kbase);
    float p[4] = {0.f, 0.f, 0.f, 0.f};
#pragma unroll
    for (int t = 0; t < 4; ++t) {
        f32x4 acc = {0.f, 0.f, 0.f, 0.f};
#pragma unroll
        for (int s = 0; s < 2; ++s) {
            bf16x8 bh = *(const bf16x8*)(g1h + (((size_t)t * 2 + s) * 64 + l) * 8);
            bf16x8 bl = *(const bf16x8*)(g1l + (((size_t)t * 2 + s) * 64 + l) * 8);
            acc = __builtin_amdgcn_mfma_f32_16x16x32_bf16(af[s], bh, acc, 0, 0, 0);
            acc = __builtin_amdgcn_mfma_f32_16x16x32_bf16(af[s], bl, acc, 0, 0, 0);
        }
        int col = t * 16 + (l & 15);
        float b = gb1[col], w2 = gw2[col];
#pragma unroll
        for (int r_ = 0; r_ < 4; ++r_) {
            float h = fmaxf(acc[r_] + b, 0.f);
            p[r_] = fmaf(h, w2, p[r_]);
        }
    }
#pragma unroll
    for (int d = 1; d < 16; d <<= 1) {
#pragma unroll
        for (int r_ = 0; r_ < 4; ++r_) p[r_] += __shfl_xor(p[r_], d, 64);
    }
    if ((l & 15) == 0) {
        float g2 = gb2[0];
#pragma unroll
        for (int r_ = 0; r_ < 4; ++r_) glogit[rows0 + (l >> 4) * 4 + r_] = p[r_] + g2;
    }
}

// ---------------- fuse: softmax over R, h_fused (bf16), aux outputs ----------------
__global__ __launch_bounds__(256) void fuse_kernel(const short* __restrict__ stack,
                                                   const float* __restrict__ glogit,
                                                   const float* __restrict__ auxw,
                                                   const float* __restrict__ auxb,
                                                   short* __restrict__ hfused,
                                                   float* __restrict__ out) {
    __shared__ float auxws[RR * 64];
    __shared__ float auxbs[RR];
    int tid = threadIdx.x;
    for (int i = tid; i < RR * 64; i += 256) auxws[i] = auxw[i];
    if (tid < RR) auxbs[tid] = auxb[tid];
    __syncthreads();
    int w = tid >> 6, lane = tid & 63;
    int n = blockIdx.x * 4 + w;
    if (n >= NN) return;
    float gl[RR];
    float m = -1e30f;
#pragma unroll
    for (int r = 0; r < RR; r++) {
        gl[r] = glogit[(size_t)n * RR + r];
        m = fmaxf(m, gl[r]);
    }
    float ssum = 0.f;
#pragma unroll
    for (int r = 0; r < RR; r++) {
        gl[r] = __expf(gl[r] - m);
        ssum += gl[r];
    }
    float inv = 1.f / ssum;
    float hf = 0.f;
#pragma unroll
    for (int r = 0; r < RR; r++) {
        float s = b2f(stack[((size_t)n * RR + r) * 64 + lane]);
        hf = fmaf(gl[r] * inv, s, hf);
        float t = s * auxws[r * 64 + lane];
#pragma unroll
        for (int d = 32; d >= 1; d >>= 1) t += __shfl_xor(t, d, 64);
        if (lane == 0) out[NN + (size_t)n * RR + r] = t + auxbs[r];
    }
    hfused[(size_t)n * 64 + lane] = f2b(hf);
}

// ---------------- cls via MFMA ----------------
__global__ __launch_bounds__(256) void cls_mfma(const short* __restrict__ hproj,
                                                const short* __restrict__ c1h,
                                                const short* __restrict__ c1l,
                                                const float* __restrict__ cb1,
                                                const float* __restrict__ cw2,
                                                const float* __restrict__ cb2,
                                                float* __restrict__ out) {
    int w = threadIdx.x >> 6, l = threadIdx.x & 63;
    int rows0 = blockIdx.x * 64 + w * 16;
    int arow = rows0 + (l & 15);
    int kbase = (l >> 4) * 8;
    bf16x8 af[2];
#pragma unroll
    for (int s = 0; s < 2; ++s) {
        bf16x8 t = {0, 0, 0, 0, 0, 0, 0, 0};
        if (arow < NN) t = *(const bf16x8*)(hproj + (size_t)arow * 64 + s * 32 + kbase);
        af[s] = t;
    }
    float p[4] = {0.f, 0.f, 0.f, 0.f};
#pragma unroll
    for (int t = 0; t < 4; ++t) {
        f32x4 acc = {0.f, 0.f, 0.f, 0.f};
#pragma unroll
        for (int s = 0; s < 2; ++s) {
            bf16x8 bh = *(const bf16x8*)(c1h + (((size_t)t * 2 + s) * 64 + l) * 8);
            bf16x8 bl = *(const bf16x8*)(c1l + (((size_t)t * 2 + s) * 64 + l) * 8);
            acc = __builtin_amdgcn_mfma_f32_16x16x32_bf16(af[s], bh, acc, 0, 0, 0);
            acc = __builtin_amdgcn_mfma_f32_16x16x32_bf16(af[s], bl, acc, 0, 0, 0);
        }
        int col = t * 16 + (l & 15);
        float b = cb1[col], w2 = cw2[col];
#pragma unroll
        for (int r_ = 0; r_ < 4; ++r_) {
            float h = fmaxf(acc[r_] + b, 0.f);
            p[r_] = fmaf(h, w2, p[r_]);
        }
    }
#pragma unroll
    for (int d = 1; d < 16; d <<= 1) {
#pragma unroll
        for (int r_ = 0; r_ < 4; ++r_) p[r_] += __shfl_xor(p[r_], d, 64);
    }
    if ((l & 15) == 0) {
        float c2 = cb2[0];
#pragma unroll
        for (int r_ = 0; r_ < 4; ++r_) {
            int row = rows0 + (l >> 4) * 4 + r_;
            if (row < NN) out[row] = p[r_] + c2;
        }
    }
}

// ---------------- host ----------------

extern "C" void kernel_launch(void* const* d_in, const int* in_sizes, int n_in,
                              void* d_out, int out_size, void* d_ws, size_t ws_size,
                              hipStream_t stream) {
    const float* x = (const float*)d_in[0];
    const int* ei = (const int*)d_in[1];
    const float* c1w = (const float*)d_in[2];
    const float* c1b = (const float*)d_in[3];
    const float* c2w = (const float*)d_in[4];
    const float* c2b = (const float*)d_in[5];
    const float* gw1 = (const float*)d_in[6];
    const float* gb1 = (const float*)d_in[7];
    const float* gw2 = (const float*)d_in[8];
    const float* gb2 = (const float*)d_in[9];
    const float* pw = (const float*)d_in[10];
    const float* pb = (const float*)d_in[11];
    const float* cw1 = (const float*)d_in[12];
    const float* cb1 = (const float*)d_in[13];
    const float* cw2 = (const float*)d_in[14];
    const float* cb2 = (const float*)d_in[15];
    const float* auxw = (const float*)d_in[16];
    const float* auxb = (const float*)d_in[17];
    float* out = (float*)d_out;

    char* wsp = (char*)d_ws;
    size_t off = 0;
    auto carve = [&](size_t bytes) -> char* {
        char* p = wsp + off;
        off += (bytes + 255) & ~(size_t)255;
        return p;
    };
    short* stack = (short*)carve((size_t)NN * RR * 64 * 2);   // bf16 [N][R][64]
    float* yb1 = (float*)carve((size_t)NN * 64 * 4);          // y1' f32; aliases zb, pairs, srcs
    short* y2b = (short*)carve((size_t)NN * 64 * 2);          // y2' bf16; also hproj
    short* wb = (short*)carve((size_t)NN * 64 * 2);           // w' bf16
    short* h1 = (short*)carve((size_t)NN * 64 * 2);           // bf16; also hfused
    short* xb = (short*)carve((size_t)NN * 128 * 2);          // x as bf16
    float* dis = (float*)carve((size_t)NN * 4);
    int* rowp = (int*)carve((size_t)(NN + 1) * 4);
    int* csr = (int*)carve((size_t)EE * 4);
    int* bcnt = (int*)carve((size_t)2 * NB * 4);              // bcntD | bcntS
    int* bbaseD = (int*)carve((size_t)(NB + 1) * 4);
    int* bcurD = (int*)carve((size_t)(NB + 1) * 4);
    int* bbaseS = (int*)carve((size_t)(NB + 1) * 4);
    int* bcurS = (int*)carve((size_t)(NB + 1) * 4);
    short* bp1h = (short*)carve((size_t)RR * 12 * 4 * 64 * 8 * 2);
    short* bp1l = (short*)carve((size_t)RR * 12 * 4 * 64 * 8 * 2);
    short* bp2h = (short*)carve((size_t)RR * 12 * 2 * 64 * 8 * 2);
    short* bp2l = (short*)carve((size_t)RR * 12 * 2 * 64 * 8 * 2);
    short* g1h = (short*)carve((size_t)512 * 8 * 2);
    short* g1l = (short*)carve((size_t)512 * 8 * 2);
    short* pwh = (short*)carve((size_t)512 * 8 * 2);
    short* pwl = (short*)carve((size_t)512 * 8 * 2);
    short* c1h = (short*)carve((size_t)512 * 8 * 2);
    short* c1l = (short*)carve((size_t)512 * 8 * 2);
    float* glogit = (float*)carve((size_t)NN * RR * 4);
    float* zb = yb1;                                  // alias (see order notes below)
    unsigned* pairs = (unsigned*)yb1;                 // EE u32 = 6.4MB, within yb1 (25.6MB)
    unsigned short* srcs = (unsigned short*)(yb1 + EE);  // EE u16 = 3.2MB, right after pairs
    short* hfused = h1;       // alias: h1 dead after relation loop
    short* hproj = y2b;       // alias: y2b dead after relation loop
    (void)in_sizes; (void)n_in; (void)out_size;

    if (off > ws_size) return;   // guard: clean absmax-fail => ws too small

    cvt_x<<<(NN * 128 / 8 + 255) / 256, 256, 0, stream>>>(x, xb);
    wpack_cheb<<<72, 256, 0, stream>>>(c1w, 128, 4, bp1h, bp1l);
    wpack_cheb<<<36, 256, 0, stream>>>(c2w, 64, 2, bp2h, bp2l);
    wpack64<<<2, 256, 0, stream>>>(gw1, g1h, g1l);
    wpack64<<<2, 256, 0, stream>>>(pw, pwh, pwl);
    wpack64<<<2, 256, 0, stream>>>(cw1, c1h, c1l);

    const int GB = 1563;   // ceil(NN/64)
    const int EB = (EE + 4095) / 4096;   // 391
    for (int r = 0; r < RR; ++r) {
        const int* src = ei + (size_t)r * 2 * EE;
        const int* dst = src + EE;
        const short* b1h = bp1h + (size_t)r * 12 * 4 * 64 * 8;
        const short* b1l = bp1l + (size_t)r * 12 * 4 * 64 * 8;
        const short* b2h = bp2h + (size_t)r * 12 * 2 * 64 * 8;
        const short* b2l = bp2l + (size_t)r * 12 * 2 * 64 * 8;

        // --- CSR build: 2-level bucket sort, LDS-only per-node atomics ---
        // (pairs/srcs live in yb1's space, dead before gemm writes yb1)
        zero_bcnt<<<1, 256, 0, stream>>>(bcnt);
        bin_count<<<EB, 256, 0, stream>>>(src, dst, bcnt, bcnt + NB);
        bin_scan<<<1, 64, 0, stream>>>(bcnt, bcnt + NB, bbaseD, bcurD, bbaseS, bcurS, rowp);
        bin_scatter<<<EB, 256, 0, stream>>>(src, dst, bcurD, bcurS, pairs, srcs);
        csr_build<<<NB, 256, 0, stream>>>(pairs, bbaseD, rowp, csr);
        deg_dis<<<NB, 256, 0, stream>>>(srcs, bbaseS, dis);

        // layer 1: tiles 4-7 -> y1' f32 (yb1), tiles 8-11 -> y2' bf16 (y2b), both dis-scaled
        gemm_mfma<128><<<GB, 256, 0, stream>>>(xb, 128, b1h, b1l, 4, 8, 4,
                                               yb1, 64, y2b, 64,
                                               nullptr, nullptr, 0, dis, 0);
        spmm_bf<1><<<NN / 8, 256, 0, stream>>>(y2b, yb1, wb, nullptr, csr, rowp, dis);
        spmm_bf<0><<<NN / 8, 256, 0, stream>>>(wb, nullptr, nullptr, zb, csr, rowp, dis);
        gemm_mfma<128><<<GB, 256, 0, stream>>>(xb, 128, b1h, b1l, 0, 4, 0,
                                               nullptr, 0, h1, 64,
                                               c1b + r * 64, zb, 64, nullptr, 1);
        // layer 2 (A = h1 bf16, K=64)
        gemm_mfma<64><<<GB, 256, 0, stream>>>(h1, 64, b2h, b2l, 4, 8, 4,
                                              yb1, 64, y2b, 64,
                                              nullptr, nullptr, 0, dis, 0);
        spmm_bf<1><<<NN / 8, 256, 0, stream>>>(y2b, yb1, wb, nullptr, csr, rowp, dis);
        spmm_bf<0><<<NN / 8, 256, 0, stream>>>(wb, nullptr, nullptr, zb, csr, rowp, dis);
        gemm_mfma<64><<<GB, 256, 0, stream>>>(h1, 64, b2h, b2l, 0, 4, 0,
                                              nullptr, 0, stack + r * 64, RR * 64,
                                              c2b + r * 64, zb, 64, nullptr, 1);
    }
    gate_mfma<<<9375, 256, 0, stream>>>(stack, g1h, g1l, gb1, gw2, gb2, glogit);
    fuse_kernel<<<NN / 4, 256, 0, stream>>>(stack, glogit, auxw, auxb, hfused, out);
    gemm_mfma<64><<<GB, 256, 0, stream>>>(hfused, 64, pwh, pwl, 0, 4, 0,
                                          nullptr, 0, hproj, 64,
                                          pb, nullptr, 0, nullptr, 1);
    cls_mfma<<<GB, 256, 0, stream>>>(hproj, c1h, c1l, cb1, cw2, cb2, out);
}

// Round 8
// 2354.167 us; speedup vs baseline: 2.8605x; 1.0214x over previous
//
#include <hip/hip_runtime.h>
#include <hip/hip_bf16.h>

#define NN 100000
#define EE 1600000
#define RR 6
#define NB 98          // node buckets of 1024

typedef __attribute__((ext_vector_type(8))) short bf16x8;
typedef __attribute__((ext_vector_type(4))) float f32x4;

__device__ inline short f2b(float x) {
    __hip_bfloat16 h = __float2bfloat16(x);
    return *reinterpret_cast<short*>(&h);
}
__device__ inline float b2f(short s) {
    __hip_bfloat16 h = *reinterpret_cast<__hip_bfloat16*>(&s);
    return __bfloat162float(h);
}

// ---------------- CSR build: 2-level bucket sort, LDS-only per-node atomics ----------------

__global__ void zero_bcnt(int* __restrict__ bcnt) {
    int i = threadIdx.x;
    if (i < 2 * NB) bcnt[i] = 0;
}

__global__ __launch_bounds__(256) void bin_count(const int* __restrict__ src,
                                                 const int* __restrict__ dst,
                                                 int* __restrict__ bcntD,
                                                 int* __restrict__ bcntS) {
    __shared__ int lcD[NB], lcS[NB];
    int t = threadIdx.x;
    for (int i = t; i < NB; i += 256) { lcD[i] = 0; lcS[i] = 0; }
    __syncthreads();
    int base = blockIdx.x * 4096;
#pragma unroll
    for (int i = 0; i < 16; ++i) {
        int e = base + i * 256 + t;
        if (e < EE) {
            atomicAdd(&lcD[dst[e] >> 10], 1);
            atomicAdd(&lcS[src[e] >> 10], 1);
        }
    }
    __syncthreads();
    for (int i = t; i < NB; i += 256) {
        if (lcD[i]) atomicAdd(&bcntD[i], lcD[i]);
        if (lcS[i]) atomicAdd(&bcntS[i], lcS[i]);
    }
}

__global__ void bin_scan(const int* __restrict__ bcntD, const int* __restrict__ bcntS,
                         int* __restrict__ bbaseD, int* __restrict__ bcurD,
                         int* __restrict__ bbaseS, int* __restrict__ bcurS,
                         int* __restrict__ rowp) {
    if (threadIdx.x == 0) {
        int run = 0;
        for (int i = 0; i < NB; ++i) { bbaseD[i] = run; bcurD[i] = run; run += bcntD[i]; }
        bbaseD[NB] = run;
        run = 0;
        for (int i = 0; i < NB; ++i) { bbaseS[i] = run; bcurS[i] = run; run += bcntS[i]; }
        bbaseS[NB] = run;
        rowp[NN] = EE;
    }
}

__global__ __launch_bounds__(256) void bin_scatter(const int* __restrict__ src,
                                                   const int* __restrict__ dst,
                                                   int* __restrict__ bcurD,
                                                   int* __restrict__ bcurS,
                                                   unsigned* __restrict__ pairs,
                                                   unsigned short* __restrict__ srcs) {
    __shared__ int lcD[NB], lbD[NB], loD[NB];
    __shared__ int lcS[NB], lbS[NB], loS[NB];
    int t = threadIdx.x;
    for (int i = t; i < NB; i += 256) { lcD[i] = 0; loD[i] = 0; lcS[i] = 0; loS[i] = 0; }
    __syncthreads();
    int base = blockIdx.x * 4096;
#pragma unroll
    for (int i = 0; i < 16; ++i) {
        int e = base + i * 256 + t;
        if (e < EE) {
            atomicAdd(&lcD[dst[e] >> 10], 1);
            atomicAdd(&lcS[src[e] >> 10], 1);
        }
    }
    __syncthreads();
    for (int i = t; i < NB; i += 256) {
        lbD[i] = lcD[i] ? atomicAdd(&bcurD[i], lcD[i]) : 0;
        lbS[i] = lcS[i] ? atomicAdd(&bcurS[i], lcS[i]) : 0;
    }
    __syncthreads();
#pragma unroll
    for (int i = 0; i < 16; ++i) {
        int e = base + i * 256 + t;
        if (e < EE) {
            int s = src[e], d = dst[e];
            int bD = d >> 10, bS = s >> 10;
            int pD = lbD[bD] + atomicAdd(&loD[bD], 1);
            if (pD >= 0 && pD < EE) pairs[pD] = ((unsigned)s << 10) | (unsigned)(d & 1023);
            int pS = lbS[bS] + atomicAdd(&loS[bS], 1);
            if (pS >= 0 && pS < EE) srcs[pS] = (unsigned short)(s & 1023);
        }
    }
}

// one block per dst-bucket: key = (dstLocal<<3)|srcSlice(src>>14) -> within-row edges sorted
// by 16K-node source slices (2.1MB of v each -> per-XCD-L2-resident gather phases in spmm).
__global__ __launch_bounds__(256) void csr_build(const unsigned* __restrict__ pairs,
                                                 const int* __restrict__ bbase,
                                                 int* __restrict__ rowp,
                                                 int* __restrict__ csr) {
    __shared__ int hist[8192];
    __shared__ int wsums[4];
    int b = blockIdx.x;
    int t = threadIdx.x;
    int p0 = bbase[b], p1 = bbase[b + 1];
    for (int i = t; i < 8192; i += 256) hist[i] = 0;
    __syncthreads();
    for (int e = p0 + t; e < p1; e += 256) {
        unsigned pr = pairs[e];
        int key = ((pr & 1023) << 3) | (int)(pr >> 24);
        atomicAdd(&hist[key], 1);
    }
    __syncthreads();
    int base = t * 32;
    int s[32];
    int run = 0;
#pragma unroll
    for (int i = 0; i < 32; ++i) { s[i] = run; run += hist[base + i]; }
    int lane = t & 63, wv = t >> 6;
    int x = run;
#pragma unroll
    for (int d = 1; d < 64; d <<= 1) {
        int y = __shfl_up(x, d, 64);
        if (lane >= d) x += y;
    }
    if (lane == 63) wsums[wv] = x;
    __syncthreads();
    int woff = 0;
    for (int wi = 0; wi < wv; ++wi) woff += wsums[wi];
    int excl = woff + x - run;    // global (within bucket) exclusive prefix of key base+0
    int r0 = b * 1024 + t * 4;    // 4 dst rows per thread (keys base, base+8, base+16, base+24)
#pragma unroll
    for (int q = 0; q < 4; ++q)
        if (r0 + q < NN) rowp[r0 + q] = p0 + excl + s[q * 8];
    __syncthreads();
#pragma unroll
    for (int i = 0; i < 32; ++i) hist[base + i] = excl + s[i];
    __syncthreads();
    for (int e = p0 + t; e < p1; e += 256) {
        unsigned pr = pairs[e];
        int key = ((pr & 1023) << 3) | (int)(pr >> 24);
        int pos = p0 + atomicAdd(&hist[key], 1);
        if (pos >= 0 && pos < EE) csr[pos] = (int)(pr >> 10);
    }
}

// one block per src-bucket: LDS hist -> dis = rsqrt(deg)
__global__ __launch_bounds__(256) void deg_dis(const unsigned short* __restrict__ srcs,
                                               const int* __restrict__ sbase,
                                               float* __restrict__ dis) {
    __shared__ int hist[1024];
    int b = blockIdx.x, t = threadIdx.x;
    int p0 = sbase[b], p1 = sbase[b + 1];
    for (int i = t; i < 1024; i += 256) hist[i] = 0;
    __syncthreads();
    for (int e = p0 + t; e < p1; e += 256)
        atomicAdd(&hist[srcs[e]], 1);
    __syncthreads();
    for (int i = t; i < 1024; i += 256) {
        int node = b * 1024 + i;
        if (node < NN) {
            int d = hist[i];
            dis[node] = d > 0 ? rsqrtf((float)d) : 0.f;
        }
    }
}

// ---------------- x -> bf16 once ----------------
__global__ __launch_bounds__(256) void cvt_x(const float* __restrict__ x, short* __restrict__ xb) {
    int i = blockIdx.x * 256 + threadIdx.x;   // per 8 elems
    if (i >= NN * 128 / 8) return;
    const float* p = x + (size_t)i * 8;
    float4 u0 = *(const float4*)p;
    float4 u1 = *(const float4*)(p + 4);
    bf16x8 t;
    t[0] = f2b(u0.x); t[1] = f2b(u0.y); t[2] = f2b(u0.z); t[3] = f2b(u0.w);
    t[4] = f2b(u1.x); t[5] = f2b(u1.y); t[6] = f2b(u1.z); t[7] = f2b(u1.w);
    *(bf16x8*)(xb + (size_t)i * 8) = t;
}

// ---------------- weight packing into MFMA B-fragment order, hi/lo bf16 ----------------
__global__ __launch_bounds__(256) void wpack_cheb(const float* __restrict__ W, int Kin, int KS,
                                                  short* __restrict__ bh, short* __restrict__ bl) {
    int idx = blockIdx.x * 256 + threadIdx.x;   // over R*12*KS*64
    int l = idx & 63;
    int q = idx >> 6;
    int s = q % KS; q /= KS;
    int t = q % 12; q /= 12;
    int r = q;
    if (r >= RR) return;
#pragma unroll
    for (int j = 0; j < 8; ++j) {
        int k = s * 32 + ((l >> 4) * 8) + j;
        int n = t * 16 + (l & 15);
        int g = n >> 6, jj = n & 63;
        float v = W[(((size_t)r * 3 + (g == 0 ? 0 : g)) * Kin + k) * 64 + jj];
        if (g == 0) v -= W[(((size_t)r * 3 + 2) * Kin + k) * 64 + jj];
        short hi = f2b(v);
        short lo = f2b(v - b2f(hi));
        bh[(size_t)idx * 8 + j] = hi;
        bl[(size_t)idx * 8 + j] = lo;
    }
}

__global__ __launch_bounds__(256) void wpack64(const float* __restrict__ W,
                                               short* __restrict__ bh, short* __restrict__ bl) {
    int idx = blockIdx.x * 256 + threadIdx.x;   // over 4*2*64 = 512
    if (idx >= 512) return;
    int l = idx & 63;
    int s = (idx >> 6) & 1;
    int t = idx >> 7;
#pragma unroll
    for (int j = 0; j < 8; ++j) {
        int k = s * 32 + ((l >> 4) * 8) + j;
        int n = t * 16 + (l & 15);
        float v = W[k * 64 + n];
        short hi = f2b(v);
        short lo = f2b(v - b2f(hi));
        bh[(size_t)idx * 8 + j] = hi;
        bl[(size_t)idx * 8 + j] = lo;
    }
}

// ---------------- MFMA GEMM (A bf16, all outputs bf16) ----------------
// tiles t<fsplit -> outA (col t*16+..), t>=fsplit -> outB (col (t-fsplit)*16+..)
template <int KDIM>
__global__ __launch_bounds__(256) void gemm_mfma(const short* __restrict__ A, int lda,
                                                 const short* __restrict__ bph,
                                                 const short* __restrict__ bplo,
                                                 int nt0, int ntn, int fsplit,
                                                 short* __restrict__ outA, int ldcA,
                                                 short* __restrict__ outB, int ldcB,
                                                 const float* __restrict__ bias,
                                                 const short* __restrict__ addb, int ldadd,
                                                 const float* __restrict__ rowscale,
                                                 int do_relu) {
    constexpr int KS = KDIM / 32;
    int w = threadIdx.x >> 6, l = threadIdx.x & 63;
    int rows0 = blockIdx.x * 64 + w * 16;
    int arow = rows0 + (l & 15);
    int kbase = (l >> 4) * 8;
    bf16x8 af[KS];
#pragma unroll
    for (int s = 0; s < KS; ++s) {
        bf16x8 t = {0, 0, 0, 0, 0, 0, 0, 0};
        if (arow < NN) t = *(const bf16x8*)(A + (size_t)arow * lda + s * 32 + kbase);
        af[s] = t;
    }
    for (int t = 0; t < ntn; ++t) {
        f32x4 acc = {0.f, 0.f, 0.f, 0.f};
        const short* bp0 = bph + (((size_t)(nt0 + t) * KS) * 64 + l) * 8;
        const short* bl0 = bplo + (((size_t)(nt0 + t) * KS) * 64 + l) * 8;
#pragma unroll
        for (int s = 0; s < KS; ++s) {
            bf16x8 bh = *(const bf16x8*)(bp0 + (size_t)s * 64 * 8);
            bf16x8 bl = *(const bf16x8*)(bl0 + (size_t)s * 64 * 8);
            acc = __builtin_amdgcn_mfma_f32_16x16x32_bf16(af[s], bh, acc, 0, 0, 0);
            acc = __builtin_amdgcn_mfma_f32_16x16x32_bf16(af[s], bl, acc, 0, 0, 0);
        }
        bool isA = (t < fsplit);
        int lcol = ((isA ? t : t - fsplit) << 4) + (l & 15);
        short* o = isA ? outA : outB;
        int ldc = isA ? ldcA : ldcB;
#pragma unroll
        for (int r_ = 0; r_ < 4; ++r_) {
            int row = rows0 + (l >> 4) * 4 + r_;
            if (row >= NN) continue;
            float v = acc[r_];
            if (bias) v += bias[lcol];
            if (addb) v += b2f(addb[(size_t)row * ldadd + lcol]);
            if (do_relu) v = fmaxf(v, 0.f);
            if (rowscale) v *= rowscale[row];
            o[(size_t)row * ldc + lcol] = f2b(v);
        }
    }
}

// ---------------- SpMM over bf16 source rows: half-wave = one row, lane = 2 feats ----------------
// MID=1: outb[row,:] = bf16( y1b[row,:] - 2*dis^2*sum v[src,:] )
// MID=0: outb[row,:] = bf16( -dis * sum v[src,:] )
template <int MID>
__global__ __launch_bounds__(256) void spmm_bf(const short* __restrict__ v,
                                               const short* __restrict__ y1b,
                                               short* __restrict__ outb,
                                               const int* __restrict__ csr,
                                               const int* __restrict__ rowp,
                                               const float* __restrict__ dis) {
    int tid = threadIdx.x;
    int wv = tid >> 6, l = tid & 63;
    int h = l >> 5, fl = l & 31;
    int row = blockIdx.x * 8 + wv * 2 + h;   // NN divisible by 8
    int s0 = max(0, rowp[row]);
    int s1 = min(EE, rowp[row + 1]);
    float a0 = 0.f, a1 = 0.f;
    int e = s0;
    for (; e + 8 <= s1; e += 8) {
        int idx[8];
#pragma unroll
        for (int i = 0; i < 8; ++i) idx[i] = csr[e + i];
        unsigned u[8];
#pragma unroll
        for (int i = 0; i < 8; ++i)
            u[i] = *(const unsigned*)(v + (size_t)idx[i] * 64 + fl * 2);
#pragma unroll
        for (int i = 0; i < 8; ++i) {
            a0 += __uint_as_float(u[i] << 16);
            a1 += __uint_as_float(u[i] & 0xffff0000u);
        }
    }
    for (; e < s1; ++e) {
        unsigned u = *(const unsigned*)(v + (size_t)csr[e] * 64 + fl * 2);
        a0 += __uint_as_float(u << 16);
        a1 += __uint_as_float(u & 0xffff0000u);
    }
    float d = dis[row];
    float v0, v1;
    if (MID) {
        unsigned yu = *(const unsigned*)(y1b + (size_t)row * 64 + fl * 2);
        float m = -2.f * d * d;
        v0 = __uint_as_float(yu << 16) + m * a0;
        v1 = __uint_as_float(yu & 0xffff0000u) + m * a1;
    } else {
        v0 = -d * a0;
        v1 = -d * a1;
    }
    unsigned o = (unsigned)(unsigned short)f2b(v0) | ((unsigned)(unsigned short)f2b(v1) << 16);
    *(unsigned*)(outb + (size_t)row * 64 + fl * 2) = o;
}

// ---------------- gate via MFMA (+ fused aux outputs) ----------------
__global__ __launch_bounds__(256) void gate_mfma(const short* __restrict__ stack,
                                                 const short* __restrict__ g1h,
                                                 const short* __restrict__ g1l,
                                                 const float* __restrict__ gb1,
                                                 const float* __restrict__ gw2,
                                                 const float* __restrict__ gb2,
                                                 const float* __restrict__ auxw,
                                                 const float* __restrict__ auxb,
                                                 float* __restrict__ glogit,
                                                 float* __restrict__ out) {
    int w = threadIdx.x >> 6, l = threadIdx.x & 63;
    int rows0 = blockIdx.x * 64 + w * 16;      // 9375*64 == 600000 exactly
    int arow = rows0 + (l & 15);
    int kbase = (l >> 4) * 8;
    bf16x8 af[2];
#pragma unroll
    for (int s = 0; s < 2; ++s)
        af[s] = *(const bf16x8*)(stack + (size_t)arow * 64 + s * 32 + kbase);
    // aux: per-lane partial dot with auxw[arow%6], reduce across the 4 k-quarters
    int rmod = arow % RR;
    float paux = 0.f;
#pragma unroll
    for (int s = 0; s < 2; ++s) {
        const float* aw = auxw + rmod * 64 + s * 32 + kbase;
#pragma unroll
        for (int j = 0; j < 8; ++j) paux = fmaf(b2f(af[s][j]), aw[j], paux);
    }
    paux += __shfl_xor(paux, 16, 64);
    paux += __shfl_xor(paux, 32, 64);
    if (l < 16) out[NN + (size_t)rows0 + l] = paux + auxb[rmod];
    // gate MLP
    float p[4] = {0.f, 0.f, 0.f, 0.f};
#pragma unroll
    for (int t = 0; t < 4; ++t) {
        f32x4 acc = {0.f, 0.f, 0.f, 0.f};
#pragma unroll
        for (int s = 0; s < 2; ++s) {
            bf16x8 bh = *(const bf16x8*)(g1h + (((size_t)t * 2 + s) * 64 + l) * 8);
            bf16x8 bl = *(const bf16x8*)(g1l + (((size_t)t * 2 + s) * 64 + l) * 8);
            acc = __builtin_amdgcn_mfma_f32_16x16x32_bf16(af[s], bh, acc, 0, 0, 0);
            acc = __builtin_amdgcn_mfma_f32_16x16x32_bf16(af[s], bl, acc, 0, 0, 0);
        }
        int col = t * 16 + (l & 15);
        float b = gb1[col], w2 = gw2[col];
#pragma unroll
        for (int r_ = 0; r_ < 4; ++r_) {
            float h = fmaxf(acc[r_] + b, 0.f);
            p[r_] = fmaf(h, w2, p[r_]);
        }
    }
#pragma unroll
    for (int d = 1; d < 16; d <<= 1) {
#pragma unroll
        for (int r_ = 0; r_ < 4; ++r_) p[r_] += __shfl_xor(p[r_], d, 64);
    }
    if ((l & 15) == 0) {
        float g2 = gb2[0];
#pragma unroll
        for (int r_ = 0; r_ < 4; ++r_) glogit[rows0 + (l >> 4) * 4 + r_] = p[r_] + g2;
    }
}

// ---------------- fuse: softmax over R -> h_fused (bf16) ----------------
__global__ __launch_bounds__(256) void fuse_kernel(const short* __restrict__ stack,
                                                   const float* __restrict__ glogit,
                                                   short* __restrict__ hfused) {
    int tid = threadIdx.x;
    int w = tid >> 6, lane = tid & 63;
    int n = blockIdx.x * 4 + w;
    if (n >= NN) return;
    float gl[RR];
    float m = -1e30f;
#pragma unroll
    for (int r = 0; r < RR; r++) {
        gl[r] = glogit[(size_t)n * RR + r];
        m = fmaxf(m, gl[r]);
    }
    float ssum = 0.f;
#pragma unroll
    for (int r = 0; r < RR; r++) {
        gl[r] = __expf(gl[r] - m);
        ssum += gl[r];
    }
    float inv = 1.f / ssum;
    float hf = 0.f;
#pragma unroll
    for (int r = 0; r < RR; r++) {
        float s = b2f(stack[((size_t)n * RR + r) * 64 + lane]);
        hf = fmaf(gl[r] * inv, s, hf);
    }
    hfused[(size_t)n * 64 + lane] = f2b(hf);
}

// ---------------- cls via MFMA ----------------
__global__ __launch_bounds__(256) void cls_mfma(const short* __restrict__ hproj,
                                                const short* __restrict__ c1h,
                                                const short* __restrict__ c1l,
                                                const float* __restrict__ cb1,
                                                const float* __restrict__ cw2,
                                                const float* __restrict__ cb2,
                                                float* __restrict__ out) {
    int w = threadIdx.x >> 6, l = threadIdx.x & 63;
    int rows0 = blockIdx.x * 64 + w * 16;
    int arow = rows0 + (l & 15);
    int kbase = (l >> 4) * 8;
    bf16x8 af[2];
#pragma unroll
    for (int s = 0; s < 2; ++s) {
        bf16x8 t = {0, 0, 0, 0, 0, 0, 0, 0};
        if (arow < NN) t = *(const bf16x8*)(hproj + (size_t)arow * 64 + s * 32 + kbase);
        af[s] = t;
    }
    float p[4] = {0.f, 0.f, 0.f, 0.f};
#pragma unroll
    for (int t = 0; t < 4; ++t) {
        f32x4 acc = {0.f, 0.f, 0.f, 0.f};
#pragma unroll
        for (int s = 0; s < 2; ++s) {
            bf16x8 bh = *(const bf16x8*)(c1h + (((size_t)t * 2 + s) * 64 + l) * 8);
            bf16x8 bl = *(const bf16x8*)(c1l + (((size_t)t * 2 + s) * 64 + l) * 8);
            acc = __builtin_amdgcn_mfma_f32_16x16x32_bf16(af[s], bh, acc, 0, 0, 0);
            acc = __builtin_amdgcn_mfma_f32_16x16x32_bf16(af[s], bl, acc, 0, 0, 0);
        }
        int col = t * 16 + (l & 15);
        float b = cb1[col], w2 = cw2[col];
#pragma unroll
        for (int r_ = 0; r_ < 4; ++r_) {
            float h = fmaxf(acc[r_] + b, 0.f);
            p[r_] = fmaf(h, w2, p[r_]);
        }
    }
#pragma unroll
    for (int d = 1; d < 16; d <<= 1) {
#pragma unroll
        for (int r_ = 0; r_ < 4; ++r_) p[r_] += __shfl_xor(p[r_], d, 64);
    }
    if ((l & 15) == 0) {
        float c2 = cb2[0];
#pragma unroll
        for (int r_ = 0; r_ < 4; ++r_) {
            int row = rows0 + (l >> 4) * 4 + r_;
            if (row < NN) out[row] = p[r_] + c2;
        }
    }
}

// ---------------- host ----------------

extern "C" void kernel_launch(void* const* d_in, const int* in_sizes, int n_in,
                              void* d_out, int out_size, void* d_ws, size_t ws_size,
                              hipStream_t stream) {
    const float* x = (const float*)d_in[0];
    const int* ei = (const int*)d_in[1];
    const float* c1w = (const float*)d_in[2];
    const float* c1b = (const float*)d_in[3];
    const float* c2w = (const float*)d_in[4];
    const float* c2b = (const float*)d_in[5];
    const float* gw1 = (const float*)d_in[6];
    const float* gb1 = (const float*)d_in[7];
    const float* gw2 = (const float*)d_in[8];
    const float* gb2 = (const float*)d_in[9];
    const float* pw = (const float*)d_in[10];
    const float* pb = (const float*)d_in[11];
    const float* cw1 = (const float*)d_in[12];
    const float* cb1 = (const float*)d_in[13];
    const float* cw2 = (const float*)d_in[14];
    const float* cb2 = (const float*)d_in[15];
    const float* auxw = (const float*)d_in[16];
    const float* auxb = (const float*)d_in[17];
    float* out = (float*)d_out;

    char* wsp = (char*)d_ws;
    size_t off = 0;
    auto carve = [&](size_t bytes) -> char* {
        char* p = wsp + off;
        off += (bytes + 255) & ~(size_t)255;
        return p;
    };
    short* stack = (short*)carve((size_t)NN * RR * 64 * 2);   // bf16 [N][R][64]
    short* y1b = (short*)carve((size_t)NN * 64 * 2);          // y1' bf16; aliases zb, pairs
    short* y2b = (short*)carve((size_t)NN * 64 * 2);          // y2' bf16; aliases srcs, hproj
    short* wb = (short*)carve((size_t)NN * 64 * 2);           // w' bf16
    short* h1 = (short*)carve((size_t)NN * 64 * 2);           // bf16; also hfused
    short* xb = (short*)carve((size_t)NN * 128 * 2);          // x as bf16
    float* dis = (float*)carve((size_t)NN * 4);
    int* rowp = (int*)carve((size_t)(NN + 1) * 4);
    int* csr = (int*)carve((size_t)EE * 4);
    int* bcnt = (int*)carve((size_t)2 * NB * 4);              // bcntD | bcntS
    int* bbaseD = (int*)carve((size_t)(NB + 1) * 4);
    int* bcurD = (int*)carve((size_t)(NB + 1) * 4);
    int* bbaseS = (int*)carve((size_t)(NB + 1) * 4);
    int* bcurS = (int*)carve((size_t)(NB + 1) * 4);
    short* bp1h = (short*)carve((size_t)RR * 12 * 4 * 64 * 8 * 2);
    short* bp1l = (short*)carve((size_t)RR * 12 * 4 * 64 * 8 * 2);
    short* bp2h = (short*)carve((size_t)RR * 12 * 2 * 64 * 8 * 2);
    short* bp2l = (short*)carve((size_t)RR * 12 * 2 * 64 * 8 * 2);
    short* g1h = (short*)carve((size_t)512 * 8 * 2);
    short* g1l = (short*)carve((size_t)512 * 8 * 2);
    short* pwh = (short*)carve((size_t)512 * 8 * 2);
    short* pwl = (short*)carve((size_t)512 * 8 * 2);
    short* c1h = (short*)carve((size_t)512 * 8 * 2);
    short* c1l = (short*)carve((size_t)512 * 8 * 2);
    float* glogit = (float*)carve((size_t)NN * RR * 4);
    short* zb = y1b;                                  // alias: y1b consumed by spmm<1> first
    unsigned* pairs = (unsigned*)y1b;                 // EE u32 = 6.4MB <= y1b 12.8MB
    unsigned short* srcs = (unsigned short*)y2b;      // EE u16 = 3.2MB <= y2b 12.8MB
    short* hfused = h1;       // alias: h1 dead after relation loop
    short* hproj = y2b;       // alias: y2b dead after relation loop
    (void)in_sizes; (void)n_in; (void)out_size;

    if (off > ws_size) return;   // guard: clean absmax-fail => ws too small

    cvt_x<<<(NN * 128 / 8 + 255) / 256, 256, 0, stream>>>(x, xb);
    wpack_cheb<<<72, 256, 0, stream>>>(c1w, 128, 4, bp1h, bp1l);
    wpack_cheb<<<36, 256, 0, stream>>>(c2w, 64, 2, bp2h, bp2l);
    wpack64<<<2, 256, 0, stream>>>(gw1, g1h, g1l);
    wpack64<<<2, 256, 0, stream>>>(pw, pwh, pwl);
    wpack64<<<2, 256, 0, stream>>>(cw1, c1h, c1l);

    const int GB = 1563;   // ceil(NN/64)
    const int EB = (EE + 4095) / 4096;   // 391
    for (int r = 0; r < RR; ++r) {
        const int* src = ei + (size_t)r * 2 * EE;
        const int* dst = src + EE;
        const short* b1h = bp1h + (size_t)r * 12 * 4 * 64 * 8;
        const short* b1l = bp1l + (size_t)r * 12 * 4 * 64 * 8;
        const short* b2h = bp2h + (size_t)r * 12 * 2 * 64 * 8;
        const short* b2l = bp2l + (size_t)r * 12 * 2 * 64 * 8;

        // --- CSR build (pairs/srcs live in y1b/y2b space, dead before gemm writes them) ---
        zero_bcnt<<<1, 256, 0, stream>>>(bcnt);
        bin_count<<<EB, 256, 0, stream>>>(src, dst, bcnt, bcnt + NB);
        bin_scan<<<1, 64, 0, stream>>>(bcnt, bcnt + NB, bbaseD, bcurD, bbaseS, bcurS, rowp);
        bin_scatter<<<EB, 256, 0, stream>>>(src, dst, bcurD, bcurS, pairs, srcs);
        csr_build<<<NB, 256, 0, stream>>>(pairs, bbaseD, rowp, csr);
        deg_dis<<<NB, 256, 0, stream>>>(srcs, bbaseS, dis);

        // layer 1: packed tiles 4-7 (W1) -> y1b, 8-11 (W2) -> y2b, both dis-scaled bf16
        gemm_mfma<128><<<GB, 256, 0, stream>>>(xb, 128, b1h, b1l, 4, 8, 4,
                                               y1b, 64, y2b, 64,
                                               nullptr, nullptr, 0, dis, 0);
        spmm_bf<1><<<NN / 8, 256, 0, stream>>>(y2b, y1b, wb, csr, rowp, dis);
        spmm_bf<0><<<NN / 8, 256, 0, stream>>>(wb, nullptr, zb, csr, rowp, dis);
        gemm_mfma<128><<<GB, 256, 0, stream>>>(xb, 128, b1h, b1l, 0, 4, 0,
                                               nullptr, 0, h1, 64,
                                               c1b + r * 64, zb, 64, nullptr, 1);
        // layer 2 (A = h1 bf16, K=64)
        gemm_mfma<64><<<GB, 256, 0, stream>>>(h1, 64, b2h, b2l, 4, 8, 4,
                                              y1b, 64, y2b, 64,
                                              nullptr, nullptr, 0, dis, 0);
        spmm_bf<1><<<NN / 8, 256, 0, stream>>>(y2b, y1b, wb, csr, rowp, dis);
        spmm_bf<0><<<NN / 8, 256, 0, stream>>>(wb, nullptr, zb, csr, rowp, dis);
        gemm_mfma<64><<<GB, 256, 0, stream>>>(h1, 64, b2h, b2l, 0, 4, 0,
                                              nullptr, 0, stack + r * 64, RR * 64,
                                              c2b + r * 64, zb, 64, nullptr, 1);
    }
    gate_mfma<<<9375, 256, 0, stream>>>(stack, g1h, g1l, gb1, gw2, gb2,
                                        auxw, auxb, glogit, out);
    fuse_kernel<<<NN / 4, 256, 0, stream>>>(stack, glogit, hfused);
    gemm_mfma<64><<<GB, 256, 0, stream>>>(hfused, 64, pwh, pwl, 0, 4, 0,
                                          nullptr, 0, hproj, 64,
                                          pb, nullptr, 0, nullptr, 1);
    cls_mfma<<<GB, 256, 0, stream>>>(hproj, c1h, c1l, cb1, cw2, cb2, out);
}

// Round 9
// 2156.514 us; speedup vs baseline: 3.1227x; 1.0917x over previous
//
#include <hip/hip_runtime.h>
#include <hip/hip_bf16.h>

#define NN 100000
#define EE 1600000
#define RR 6
#define NBK 391        // dst/src buckets of 256 nodes
#define EB 391         // edge blocks (4096 edges each)

typedef __attribute__((ext_vector_type(8))) short bf16x8;
typedef __attribute__((ext_vector_type(4))) float f32x4;

__device__ inline short f2b(float x) {
    __hip_bfloat16 h = __float2bfloat16(x);
    return *reinterpret_cast<short*>(&h);
}
__device__ inline float b2f(short s) {
    __hip_bfloat16 h = *reinterpret_cast<__hip_bfloat16*>(&s);
    return __bfloat162float(h);
}

// ---------------- CSR build ----------------

__global__ __launch_bounds__(256) void zero_cnts(int* p, int n) {
    int i = blockIdx.x * 256 + threadIdx.x;
    if (i < n) p[i] = 0;
}

__global__ __launch_bounds__(256) void bin_count(const int* __restrict__ src,
                                                 const int* __restrict__ dst,
                                                 int* __restrict__ bcntD,
                                                 int* __restrict__ bcntS) {
    __shared__ int lcD[NBK], lcS[NBK];
    int t = threadIdx.x;
    for (int i = t; i < NBK; i += 256) { lcD[i] = 0; lcS[i] = 0; }
    __syncthreads();
    int base = blockIdx.x * 4096;
#pragma unroll
    for (int i = 0; i < 16; ++i) {
        int e = base + i * 256 + t;
        if (e < EE) {
            atomicAdd(&lcD[dst[e] >> 8], 1);
            atomicAdd(&lcS[src[e] >> 8], 1);
        }
    }
    __syncthreads();
    for (int i = t; i < NBK; i += 256) {
        if (lcD[i]) atomicAdd(&bcntD[i], lcD[i]);
        if (lcS[i]) atomicAdd(&bcntS[i], lcS[i]);
    }
}

// scatter edges into dst-bucket regions (pairs) and src-bucket regions (srcs u8).
// bucket bases re-derived in-LDS from final bcnt; chunks reserved via global bcur.
__global__ __launch_bounds__(256) void bin_scatter(const int* __restrict__ src,
                                                   const int* __restrict__ dst,
                                                   const int* __restrict__ bcntD,
                                                   const int* __restrict__ bcntS,
                                                   int* __restrict__ bcurD,
                                                   int* __restrict__ bcurS,
                                                   unsigned* __restrict__ pairs,
                                                   unsigned char* __restrict__ srcs) {
    __shared__ int bbD[NBK], bbS[NBK];
    __shared__ int lcD[NBK], lbD[NBK], loD[NBK];
    __shared__ int lcS[NBK], lbS[NBK], loS[NBK];
    int t = threadIdx.x;
    for (int i = t; i < NBK; i += 256) { lcD[i] = 0; loD[i] = 0; lcS[i] = 0; loS[i] = 0; }
    // wave 0: exclusive prefix of bcntD/bcntS into bbD/bbS
    if (t < 64) {
        int lane = t;
        int runD = 0, runS = 0;
        for (int c = 0; c < 7; ++c) {
            int i = c * 64 + lane;
            int vD = (i < NBK) ? bcntD[i] : 0;
            int vS = (i < NBK) ? bcntS[i] : 0;
            int xD = vD, xS = vS;
#pragma unroll
            for (int d = 1; d < 64; d <<= 1) {
                int yD = __shfl_up(xD, d, 64);
                int yS = __shfl_up(xS, d, 64);
                if (lane >= d) { xD += yD; xS += yS; }
            }
            if (i < NBK) { bbD[i] = runD + xD - vD; bbS[i] = runS + xS - vS; }
            runD += __shfl(xD, 63, 64);
            runS += __shfl(xS, 63, 64);
        }
    }
    __syncthreads();
    int base = blockIdx.x * 4096;
#pragma unroll
    for (int i = 0; i < 16; ++i) {
        int e = base + i * 256 + t;
        if (e < EE) {
            atomicAdd(&lcD[dst[e] >> 8], 1);
            atomicAdd(&lcS[src[e] >> 8], 1);
        }
    }
    __syncthreads();
    for (int i = t; i < NBK; i += 256) {
        lbD[i] = lcD[i] ? atomicAdd(&bcurD[i], lcD[i]) : 0;
        lbS[i] = lcS[i] ? atomicAdd(&bcurS[i], lcS[i]) : 0;
    }
    __syncthreads();
#pragma unroll
    for (int i = 0; i < 16; ++i) {
        int e = base + i * 256 + t;
        if (e < EE) {
            int s = src[e], d = dst[e];
            int bD = d >> 8, bS = s >> 8;
            int pD = bbD[bD] + lbD[bD] + atomicAdd(&loD[bD], 1);
            if (pD >= 0 && pD < EE) pairs[pD] = ((unsigned)s << 8) | (unsigned)(d & 255);
            int pS = bbS[bS] + lbS[bS] + atomicAdd(&loS[bS], 1);
            if (pS >= 0 && pS < EE) srcs[pS] = (unsigned char)(s & 255);
        }
    }
}

// one block per dst-bucket (256 rows): key = dstLocal*8 | srcSlice(src>>14).
// thread t owns row t: local scan -> rowp; LDS-cursor scatter -> csr.
__global__ __launch_bounds__(256) void csr_build(const unsigned* __restrict__ pairs,
                                                 const int* __restrict__ bcntD,
                                                 int* __restrict__ rowp,
                                                 int* __restrict__ csr) {
    __shared__ int hist[2048];
    __shared__ int wsums[4];
    __shared__ int sh_p0;
    int b = blockIdx.x, t = threadIdx.x;
    // wave 0: p0 = sum_{i<b} bcntD[i]
    if (t < 64) {
        int s = 0;
        for (int i = t; i < b; i += 64) s += bcntD[i];
#pragma unroll
        for (int d = 32; d >= 1; d >>= 1) s += __shfl_xor(s, d, 64);
        if (t == 0) sh_p0 = s;
    }
    for (int i = t; i < 2048; i += 256) hist[i] = 0;
    __syncthreads();
    int p0 = sh_p0;
    int p1 = p0 + bcntD[b];
    for (int e = p0 + t; e < p1; e += 256) {
        unsigned pr = pairs[e];
        int key = ((pr & 255) << 3) | (int)((pr >> 8) >> 14);
        atomicAdd(&hist[key], 1);
    }
    __syncthreads();
    int s[8];
    int run = 0;
#pragma unroll
    for (int i = 0; i < 8; ++i) { s[i] = run; run += hist[t * 8 + i]; }
    int lane = t & 63, wv = t >> 6;
    int x = run;
#pragma unroll
    for (int d = 1; d < 64; d <<= 1) {
        int y = __shfl_up(x, d, 64);
        if (lane >= d) x += y;
    }
    if (lane == 63) wsums[wv] = x;
    __syncthreads();
    int woff = 0;
    for (int wi = 0; wi < wv; ++wi) woff += wsums[wi];
    int excl = woff + x - run;        // exclusive prefix (within bucket) of this row
    int row = b * 256 + t;
    if (row < NN) rowp[row] = p0 + excl;
    if (b == 0 && t == 0) rowp[NN] = EE;
    __syncthreads();
#pragma unroll
    for (int i = 0; i < 8; ++i) hist[t * 8 + i] = p0 + excl + s[i];   // absolute cursors
    __syncthreads();
    for (int e = p0 + t; e < p1; e += 256) {
        unsigned pr = pairs[e];
        int key = ((pr & 255) << 3) | (int)((pr >> 8) >> 14);
        int pos = atomicAdd(&hist[key], 1);
        if (pos >= 0 && pos < EE) csr[pos] = (int)(pr >> 8);
    }
}

// one block per src-bucket: LDS hist -> dis = rsqrt(deg)
__global__ __launch_bounds__(256) void deg_dis(const unsigned char* __restrict__ srcs,
                                               const int* __restrict__ bcntS,
                                               float* __restrict__ dis) {
    __shared__ int hist[256];
    __shared__ int sh_p0;
    int b = blockIdx.x, t = threadIdx.x;
    if (t < 64) {
        int s = 0;
        for (int i = t; i < b; i += 64) s += bcntS[i];
#pragma unroll
        for (int d = 32; d >= 1; d >>= 1) s += __shfl_xor(s, d, 64);
        if (t == 0) sh_p0 = s;
    }
    hist[t] = 0;
    __syncthreads();
    int p0 = sh_p0;
    int p1 = p0 + bcntS[b];
    for (int e = p0 + t; e < p1; e += 256)
        atomicAdd(&hist[srcs[e]], 1);
    __syncthreads();
    int node = b * 256 + t;
    if (node < NN) {
        int d = hist[t];
        dis[node] = d > 0 ? rsqrtf((float)d) : 0.f;
    }
}

// ---------------- x -> bf16 once ----------------
__global__ __launch_bounds__(256) void cvt_x(const float* __restrict__ x, short* __restrict__ xb) {
    int i = blockIdx.x * 256 + threadIdx.x;   // per 8 elems
    if (i >= NN * 128 / 8) return;
    const float* p = x + (size_t)i * 8;
    float4 u0 = *(const float4*)p;
    float4 u1 = *(const float4*)(p + 4);
    bf16x8 t;
    t[0] = f2b(u0.x); t[1] = f2b(u0.y); t[2] = f2b(u0.z); t[3] = f2b(u0.w);
    t[4] = f2b(u1.x); t[5] = f2b(u1.y); t[6] = f2b(u1.z); t[7] = f2b(u1.w);
    *(bf16x8*)(xb + (size_t)i * 8) = t;
}

// ---------------- weight packing into MFMA B-fragment order, hi/lo bf16 ----------------
__global__ __launch_bounds__(256) void wpack_cheb(const float* __restrict__ W, int Kin, int KS,
                                                  short* __restrict__ bh, short* __restrict__ bl) {
    int idx = blockIdx.x * 256 + threadIdx.x;   // over R*12*KS*64
    int l = idx & 63;
    int q = idx >> 6;
    int s = q % KS; q /= KS;
    int t = q % 12; q /= 12;
    int r = q;
    if (r >= RR) return;
#pragma unroll
    for (int j = 0; j < 8; ++j) {
        int k = s * 32 + ((l >> 4) * 8) + j;
        int n = t * 16 + (l & 15);
        int g = n >> 6, jj = n & 63;
        float v = W[(((size_t)r * 3 + (g == 0 ? 0 : g)) * Kin + k) * 64 + jj];
        if (g == 0) v -= W[(((size_t)r * 3 + 2) * Kin + k) * 64 + jj];
        short hi = f2b(v);
        short lo = f2b(v - b2f(hi));
        bh[(size_t)idx * 8 + j] = hi;
        bl[(size_t)idx * 8 + j] = lo;
    }
}

__global__ __launch_bounds__(256) void wpack64(const float* __restrict__ W,
                                               short* __restrict__ bh, short* __restrict__ bl) {
    int idx = blockIdx.x * 256 + threadIdx.x;   // over 4*2*64 = 512
    if (idx >= 512) return;
    int l = idx & 63;
    int s = (idx >> 6) & 1;
    int t = idx >> 7;
#pragma unroll
    for (int j = 0; j < 8; ++j) {
        int k = s * 32 + ((l >> 4) * 8) + j;
        int n = t * 16 + (l & 15);
        float v = W[k * 64 + n];
        short hi = f2b(v);
        short lo = f2b(v - b2f(hi));
        bh[(size_t)idx * 8 + j] = hi;
        bl[(size_t)idx * 8 + j] = lo;
    }
}

// ---------------- MFMA GEMM (A bf16, up to 3 bf16 outputs) ----------------
// tiles t<s1 -> o0, t<s2 -> o1, else o2. rowscale applied only to tiles >= scale_from.
template <int KDIM>
__global__ __launch_bounds__(256) void gemm_mfma(const short* __restrict__ A, int lda,
                                                 const short* __restrict__ bph,
                                                 const short* __restrict__ bplo,
                                                 int nt0, int ntn, int s1, int s2,
                                                 short* __restrict__ o0, int ld0,
                                                 short* __restrict__ o1, int ld1,
                                                 short* __restrict__ o2, int ld2,
                                                 const float* __restrict__ bias,
                                                 int scale_from,
                                                 const float* __restrict__ rowscale,
                                                 int do_relu) {
    constexpr int KS = KDIM / 32;
    int w = threadIdx.x >> 6, l = threadIdx.x & 63;
    int rows0 = blockIdx.x * 64 + w * 16;
    int arow = rows0 + (l & 15);
    int kbase = (l >> 4) * 8;
    bf16x8 af[KS];
#pragma unroll
    for (int s = 0; s < KS; ++s) {
        bf16x8 t = {0, 0, 0, 0, 0, 0, 0, 0};
        if (arow < NN) t = *(const bf16x8*)(A + (size_t)arow * lda + s * 32 + kbase);
        af[s] = t;
    }
    for (int t = 0; t < ntn; ++t) {
        f32x4 acc = {0.f, 0.f, 0.f, 0.f};
        const short* bp0 = bph + (((size_t)(nt0 + t) * KS) * 64 + l) * 8;
        const short* bl0 = bplo + (((size_t)(nt0 + t) * KS) * 64 + l) * 8;
#pragma unroll
        for (int s = 0; s < KS; ++s) {
            bf16x8 bh = *(const bf16x8*)(bp0 + (size_t)s * 64 * 8);
            bf16x8 bl = *(const bf16x8*)(bl0 + (size_t)s * 64 * 8);
            acc = __builtin_amdgcn_mfma_f32_16x16x32_bf16(af[s], bh, acc, 0, 0, 0);
            acc = __builtin_amdgcn_mfma_f32_16x16x32_bf16(af[s], bl, acc, 0, 0, 0);
        }
        short* o;
        int ldc, tl;
        if (t < s1) { o = o0; ldc = ld0; tl = t; }
        else if (t < s2) { o = o1; ldc = ld1; tl = t - s1; }
        else { o = o2; ldc = ld2; tl = t - s2; }
        int lcol = (tl << 4) + (l & 15);
        bool scl = (rowscale != nullptr) && (t >= scale_from);
#pragma unroll
        for (int r_ = 0; r_ < 4; ++r_) {
            int row = rows0 + (l >> 4) * 4 + r_;
            if (row >= NN) continue;
            float v = acc[r_];
            if (bias) v += bias[lcol];
            if (do_relu) v = fmaxf(v, 0.f);
            if (scl) v *= rowscale[row];
            o[(size_t)row * ldc + lcol] = f2b(v);
        }
    }
}

// ---------------- SpMM over bf16 source rows: half-wave = one row, lane = 2 feats ----------------
// MID=1: outb[row,:] = bf16( y1b[row,:] - 2*dis^2*sum v[src,:] )
// MID=0: outb[row,:] = bf16( -dis * sum v[src,:] )
template <int MID>
__global__ __launch_bounds__(256) void spmm_bf(const short* __restrict__ v,
                                               const short* __restrict__ y1b,
                                               short* __restrict__ outb,
                                               const int* __restrict__ csr,
                                               const int* __restrict__ rowp,
                                               const float* __restrict__ dis) {
    int tid = threadIdx.x;
    int wv = tid >> 6, l = tid & 63;
    int h = l >> 5, fl = l & 31;
    int row = blockIdx.x * 8 + wv * 2 + h;   // NN divisible by 8
    int s0 = max(0, rowp[row]);
    int s1 = min(EE, rowp[row + 1]);
    float a0 = 0.f, a1 = 0.f;
    int e = s0;
    for (; e + 8 <= s1; e += 8) {
        int idx[8];
#pragma unroll
        for (int i = 0; i < 8; ++i) idx[i] = csr[e + i];
        unsigned u[8];
#pragma unroll
        for (int i = 0; i < 8; ++i)
            u[i] = *(const unsigned*)(v + (size_t)idx[i] * 64 + fl * 2);
#pragma unroll
        for (int i = 0; i < 8; ++i) {
            a0 += __uint_as_float(u[i] << 16);
            a1 += __uint_as_float(u[i] & 0xffff0000u);
        }
    }
    for (; e < s1; ++e) {
        unsigned u = *(const unsigned*)(v + (size_t)csr[e] * 64 + fl * 2);
        a0 += __uint_as_float(u << 16);
        a1 += __uint_as_float(u & 0xffff0000u);
    }
    float d = dis[row];
    float v0, v1;
    if (MID) {
        unsigned yu = *(const unsigned*)(y1b + (size_t)row * 64 + fl * 2);
        float m = -2.f * d * d;
        v0 = __uint_as_float(yu << 16) + m * a0;
        v1 = __uint_as_float(yu & 0xffff0000u) + m * a1;
    } else {
        v0 = -d * a0;
        v1 = -d * a1;
    }
    unsigned o = (unsigned)(unsigned short)f2b(v0) | ((unsigned)(unsigned short)f2b(v1) << 16);
    *(unsigned*)(outb + (size_t)row * 64 + fl * 2) = o;
}

// ---------------- elementwise: out = relu(t0 + s + bias), bf16 in/out ----------------
__global__ __launch_bounds__(256) void ew_h(const short* __restrict__ t0,
                                            const short* __restrict__ s,
                                            const float* __restrict__ bias,
                                            short* __restrict__ out, int ldc) {
    int i = blockIdx.x * 256 + threadIdx.x;   // over NN*32 u32 groups
    if (i >= NN * 32) return;
    int row = i >> 5, c2 = (i & 31) * 2;
    unsigned a = *(const unsigned*)(t0 + (size_t)row * 64 + c2);
    unsigned b = *(const unsigned*)(s + (size_t)row * 64 + c2);
    float v0 = __uint_as_float(a << 16) + __uint_as_float(b << 16) + bias[c2];
    float v1 = __uint_as_float(a & 0xffff0000u) + __uint_as_float(b & 0xffff0000u) + bias[c2 + 1];
    v0 = fmaxf(v0, 0.f);
    v1 = fmaxf(v1, 0.f);
    unsigned o = (unsigned)(unsigned short)f2b(v0) | ((unsigned)(unsigned short)f2b(v1) << 16);
    *(unsigned*)(out + (size_t)row * ldc + c2) = o;
}

// ---------------- gate via MFMA (+ fused aux outputs) ----------------
__global__ __launch_bounds__(256) void gate_mfma(const short* __restrict__ stack,
                                                 const short* __restrict__ g1h,
                                                 const short* __restrict__ g1l,
                                                 const float* __restrict__ gb1,
                                                 const float* __restrict__ gw2,
                                                 const float* __restrict__ gb2,
                                                 const float* __restrict__ auxw,
                                                 const float* __restrict__ auxb,
                                                 float* __restrict__ glogit,
                                                 float* __restrict__ out) {
    int w = threadIdx.x >> 6, l = threadIdx.x & 63;
    int rows0 = blockIdx.x * 64 + w * 16;      // 9375*64 == 600000 exactly
    int arow = rows0 + (l & 15);
    int kbase = (l >> 4) * 8;
    bf16x8 af[2];
#pragma unroll
    for (int s = 0; s < 2; ++s)
        af[s] = *(const bf16x8*)(stack + (size_t)arow * 64 + s * 32 + kbase);
    int rmod = arow % RR;
    float paux = 0.f;
#pragma unroll
    for (int s = 0; s < 2; ++s) {
        const float* aw = auxw + rmod * 64 + s * 32 + kbase;
#pragma unroll
        for (int j = 0; j < 8; ++j) paux = fmaf(b2f(af[s][j]), aw[j], paux);
    }
    paux += __shfl_xor(paux, 16, 64);
    paux += __shfl_xor(paux, 32, 64);
    if (l < 16) out[NN + (size_t)rows0 + l] = paux + auxb[rmod];
    float p[4] = {0.f, 0.f, 0.f, 0.f};
#pragma unroll
    for (int t = 0; t < 4; ++t) {
        f32x4 acc = {0.f, 0.f, 0.f, 0.f};
#pragma unroll
        for (int s = 0; s < 2; ++s) {
            bf16x8 bh = *(const bf16x8*)(g1h + (((size_t)t * 2 + s) * 64 + l) * 8);
            bf16x8 bl = *(const bf16x8*)(g1l + (((size_t)t * 2 + s) * 64 + l) * 8);
            acc = __builtin_amdgcn_mfma_f32_16x16x32_bf16(af[s], bh, acc, 0, 0, 0);
            acc = __builtin_amdgcn_mfma_f32_16x16x32_bf16(af[s], bl, acc, 0, 0, 0);
        }
        int col = t * 16 + (l & 15);
        float b = gb1[col], w2 = gw2[col];
#pragma unroll
        for (int r_ = 0; r_ < 4; ++r_) {
            float h = fmaxf(acc[r_] + b, 0.f);
            p[r_] = fmaf(h, w2, p[r_]);
        }
    }
#pragma unroll
    for (int d = 1; d < 16; d <<= 1) {
#pragma unroll
        for (int r_ = 0; r_ < 4; ++r_) p[r_] += __shfl_xor(p[r_], d, 64);
    }
    if ((l & 15) == 0) {
        float g2 = gb2[0];
#pragma unroll
        for (int r_ = 0; r_ < 4; ++r_) glogit[rows0 + (l >> 4) * 4 + r_] = p[r_] + g2;
    }
}

// ---------------- fuse: softmax over R -> h_fused (bf16) ----------------
__global__ __launch_bounds__(256) void fuse_kernel(const short* __restrict__ stack,
                                                   const float* __restrict__ glogit,
                                                   short* __restrict__ hfused) {
    int tid = threadIdx.x;
    int w = tid >> 6, lane = tid & 63;
    int n = blockIdx.x * 4 + w;
    if (n >= NN) return;
    float gl[RR];
    float m = -1e30f;
#pragma unroll
    for (int r = 0; r < RR; r++) {
        gl[r] = glogit[(size_t)n * RR + r];
        m = fmaxf(m, gl[r]);
    }
    float ssum = 0.f;
#pragma unroll
    for (int r = 0; r < RR; r++) {
        gl[r] = __expf(gl[r] - m);
        ssum += gl[r];
    }
    float inv = 1.f / ssum;
    float hf = 0.f;
#pragma unroll
    for (int r = 0; r < RR; r++) {
        float s = b2f(stack[((size_t)n * RR + r) * 64 + lane]);
        hf = fmaf(gl[r] * inv, s, hf);
    }
    hfused[(size_t)n * 64 + lane] = f2b(hf);
}

// ---------------- cls via MFMA ----------------
__global__ __launch_bounds__(256) void cls_mfma(const short* __restrict__ hproj,
                                                const short* __restrict__ c1h,
                                                const short* __restrict__ c1l,
                                                const float* __restrict__ cb1,
                                                const float* __restrict__ cw2,
                                                const float* __restrict__ cb2,
                                                float* __restrict__ out) {
    int w = threadIdx.x >> 6, l = threadIdx.x & 63;
    int rows0 = blockIdx.x * 64 + w * 16;
    int arow = rows0 + (l & 15);
    int kbase = (l >> 4) * 8;
    bf16x8 af[2];
#pragma unroll
    for (int s = 0; s < 2; ++s) {
        bf16x8 t = {0, 0, 0, 0, 0, 0, 0, 0};
        if (arow < NN) t = *(const bf16x8*)(hproj + (size_t)arow * 64 + s * 32 + kbase);
        af[s] = t;
    }
    float p[4] = {0.f, 0.f, 0.f, 0.f};
#pragma unroll
    for (int t = 0; t < 4; ++t) {
        f32x4 acc = {0.f, 0.f, 0.f, 0.f};
#pragma unroll
        for (int s = 0; s < 2; ++s) {
            bf16x8 bh = *(const bf16x8*)(c1h + (((size_t)t * 2 + s) * 64 + l) * 8);
            bf16x8 bl = *(const bf16x8*)(c1l + (((size_t)t * 2 + s) * 64 + l) * 8);
            acc = __builtin_amdgcn_mfma_f32_16x16x32_bf16(af[s], bh, acc, 0, 0, 0);
            acc = __builtin_amdgcn_mfma_f32_16x16x32_bf16(af[s], bl, acc, 0, 0, 0);
        }
        int col = t * 16 + (l & 15);
        float b = cb1[col], w2 = cw2[col];
#pragma unroll
        for (int r_ = 0; r_ < 4; ++r_) {
            float h = fmaxf(acc[r_] + b, 0.f);
            p[r_] = fmaf(h, w2, p[r_]);
        }
    }
#pragma unroll
    for (int d = 1; d < 16; d <<= 1) {
#pragma unroll
        for (int r_ = 0; r_ < 4; ++r_) p[r_] += __shfl_xor(p[r_], d, 64);
    }
    if ((l & 15) == 0) {
        float c2 = cb2[0];
#pragma unroll
        for (int r_ = 0; r_ < 4; ++r_) {
            int row = rows0 + (l >> 4) * 4 + r_;
            if (row < NN) out[row] = p[r_] + c2;
        }
    }
}

// ---------------- host ----------------

extern "C" void kernel_launch(void* const* d_in, const int* in_sizes, int n_in,
                              void* d_out, int out_size, void* d_ws, size_t ws_size,
                              hipStream_t stream) {
    const float* x = (const float*)d_in[0];
    const int* ei = (const int*)d_in[1];
    const float* c1w = (const float*)d_in[2];
    const float* c1b = (const float*)d_in[3];
    const float* c2w = (const float*)d_in[4];
    const float* c2b = (const float*)d_in[5];
    const float* gw1 = (const float*)d_in[6];
    const float* gb1 = (const float*)d_in[7];
    const float* gw2 = (const float*)d_in[8];
    const float* gb2 = (const float*)d_in[9];
    const float* pw = (const float*)d_in[10];
    const float* pb = (const float*)d_in[11];
    const float* cw1 = (const float*)d_in[12];
    const float* cb1 = (const float*)d_in[13];
    const float* cw2 = (const float*)d_in[14];
    const float* cb2 = (const float*)d_in[15];
    const float* auxw = (const float*)d_in[16];
    const float* auxb = (const float*)d_in[17];
    float* out = (float*)d_out;

    char* wsp = (char*)d_ws;
    size_t off = 0;
    auto carve = [&](size_t bytes) -> char* {
        char* p = wsp + off;
        off += (bytes + 255) & ~(size_t)255;
        return p;
    };
    short* stack = (short*)carve((size_t)NN * RR * 64 * 2);   // bf16 [N][R][64]
    short* y1b = (short*)carve((size_t)NN * 64 * 2);          // y1' bf16; aliases zb, pairs
    short* y2b = (short*)carve((size_t)NN * 64 * 2);          // y2' bf16; aliases srcs, hproj
    short* wb = (short*)carve((size_t)NN * 64 * 2);           // w' bf16
    short* h1 = (short*)carve((size_t)NN * 64 * 2);           // bf16; also hfused
    short* t0b = (short*)carve((size_t)NN * 64 * 2);          // x@(W0-W2) bf16
    short* xb = (short*)carve((size_t)NN * 128 * 2);          // x as bf16
    float* dis = (float*)carve((size_t)NN * 4);
    int* rowp = (int*)carve((size_t)(NN + 1) * 4);
    int* csr = (int*)carve((size_t)EE * 4);
    int* cnts = (int*)carve((size_t)4 * RR * NBK * 4);        // bcntD|bcntS|bcurD|bcurS per rel
    short* bp1h = (short*)carve((size_t)RR * 12 * 4 * 64 * 8 * 2);
    short* bp1l = (short*)carve((size_t)RR * 12 * 4 * 64 * 8 * 2);
    short* bp2h = (short*)carve((size_t)RR * 12 * 2 * 64 * 8 * 2);
    short* bp2l = (short*)carve((size_t)RR * 12 * 2 * 64 * 8 * 2);
    short* g1h = (short*)carve((size_t)512 * 8 * 2);
    short* g1l = (short*)carve((size_t)512 * 8 * 2);
    short* pwh = (short*)carve((size_t)512 * 8 * 2);
    short* pwl = (short*)carve((size_t)512 * 8 * 2);
    short* c1h = (short*)carve((size_t)512 * 8 * 2);
    short* c1l = (short*)carve((size_t)512 * 8 * 2);
    float* glogit = (float*)carve((size_t)NN * RR * 4);
    short* zb = y1b;                                  // alias: y1' consumed by spmm<1> first
    unsigned* pairs = (unsigned*)y1b;                 // EE u32 = 6.4MB <= y1b 12.8MB
    unsigned char* srcs = (unsigned char*)y2b;        // EE u8 = 1.6MB <= y2b 12.8MB
    short* hfused = h1;       // alias: h1 dead after relation loop
    short* hproj = y2b;       // alias: y2b dead after relation loop
    (void)in_sizes; (void)n_in; (void)out_size;

    if (off > ws_size) return;   // guard: clean absmax-fail => ws too small

    zero_cnts<<<(4 * RR * NBK + 255) / 256, 256, 0, stream>>>(cnts, 4 * RR * NBK);
    cvt_x<<<(NN * 128 / 8 + 255) / 256, 256, 0, stream>>>(x, xb);
    wpack_cheb<<<72, 256, 0, stream>>>(c1w, 128, 4, bp1h, bp1l);
    wpack_cheb<<<36, 256, 0, stream>>>(c2w, 64, 2, bp2h, bp2l);
    wpack64<<<2, 256, 0, stream>>>(gw1, g1h, g1l);
    wpack64<<<2, 256, 0, stream>>>(pw, pwh, pwl);
    wpack64<<<2, 256, 0, stream>>>(cw1, c1h, c1l);

    const int GB = 1563;   // ceil(NN/64)
    for (int r = 0; r < RR; ++r) {
        const int* src = ei + (size_t)r * 2 * EE;
        const int* dst = src + EE;
        const short* b1h = bp1h + (size_t)r * 12 * 4 * 64 * 8;
        const short* b1l = bp1l + (size_t)r * 12 * 4 * 64 * 8;
        const short* b2h = bp2h + (size_t)r * 12 * 2 * 64 * 8;
        const short* b2l = bp2l + (size_t)r * 12 * 2 * 64 * 8;
        int* bcntD = cnts + (size_t)(4 * r + 0) * NBK;
        int* bcntS = cnts + (size_t)(4 * r + 1) * NBK;
        int* bcurD = cnts + (size_t)(4 * r + 2) * NBK;
        int* bcurS = cnts + (size_t)(4 * r + 3) * NBK;

        // --- CSR build (pairs/srcs live in y1b/y2b space, dead before gemm writes them) ---
        bin_count<<<EB, 256, 0, stream>>>(src, dst, bcntD, bcntS);
        bin_scatter<<<EB, 256, 0, stream>>>(src, dst, bcntD, bcntS, bcurD, bcurS, pairs, srcs);
        csr_build<<<NBK, 256, 0, stream>>>(pairs, bcntD, rowp, csr);
        deg_dis<<<NBK, 256, 0, stream>>>(srcs, bcntS, dis);

        // layer 1: one pass over xb -> t0 (unscaled), y1', y2' (dis-scaled), all bf16
        gemm_mfma<128><<<GB, 256, 0, stream>>>(xb, 128, b1h, b1l, 0, 12, 4, 8,
                                               t0b, 64, y1b, 64, y2b, 64,
                                               nullptr, 4, dis, 0);
        spmm_bf<1><<<NN / 8, 256, 0, stream>>>(y2b, y1b, wb, csr, rowp, dis);
        spmm_bf<0><<<NN / 8, 256, 0, stream>>>(wb, nullptr, zb, csr, rowp, dis);
        ew_h<<<(NN * 32 + 255) / 256, 256, 0, stream>>>(t0b, zb, c1b + r * 64, h1, 64);
        // layer 2 (A = h1 bf16, K=64)
        gemm_mfma<64><<<GB, 256, 0, stream>>>(h1, 64, b2h, b2l, 0, 12, 4, 8,
                                              t0b, 64, y1b, 64, y2b, 64,
                                              nullptr, 4, dis, 0);
        spmm_bf<1><<<NN / 8, 256, 0, stream>>>(y2b, y1b, wb, csr, rowp, dis);
        spmm_bf<0><<<NN / 8, 256, 0, stream>>>(wb, nullptr, zb, csr, rowp, dis);
        ew_h<<<(NN * 32 + 255) / 256, 256, 0, stream>>>(t0b, zb, c2b + r * 64,
                                                        stack + r * 64, RR * 64);
    }
    gate_mfma<<<9375, 256, 0, stream>>>(stack, g1h, g1l, gb1, gw2, gb2,
                                        auxw, auxb, glogit, out);
    fuse_kernel<<<NN / 4, 256, 0, stream>>>(stack, glogit, hfused);
    gemm_mfma<64><<<GB, 256, 0, stream>>>(hfused, 64, pwh, pwl, 0, 4, 4, 8,
                                          hproj, 64, nullptr, 0, nullptr, 0,
                                          pb, 99, nullptr, 1);
    cls_mfma<<<GB, 256, 0, stream>>>(hproj, c1h, c1l, cb1, cw2, cb2, out);
}